// Round 4
// baseline (1184.462 us; speedup 1.0000x reference)
//
#include <hip/hip_runtime.h>
#include <hip/hip_fp16.h>
#include <stdint.h>

#define NN      100000
#define EE      1600000
#define NFEATC  128
#define NHIDC   32
#define NHEADSC 8
#define NCLASSC 40
#define FDIM    256     // NHEADS*NHID
#define NBLK    ((NN+255)/256)   // 391

typedef unsigned short u16;
typedef __attribute__((ext_vector_type(8))) short bf16x8;
typedef __attribute__((ext_vector_type(4))) float f32x4;

__device__ __forceinline__ float b2f(u16 u){ union{uint32_t i; float f;} v; v.i=((uint32_t)u)<<16; return v.f; }
__device__ __forceinline__ float lof(uint32_t u){ union{uint32_t i; float f;} v; v.i=u<<16; return v.f; }
__device__ __forceinline__ float hif(uint32_t u){ union{uint32_t i; float f;} v; v.i=u&0xFFFF0000u; return v.f; }
__device__ __forceinline__ u16 f2b(float f){ union{float f; uint32_t i;} v; v.f=f; uint32_t x=v.i; return (u16)((x + 0x7FFFu + ((x>>16)&1u))>>16); }
__device__ __forceinline__ uint32_t pack2(float a, float b){ return (uint32_t)f2b(a) | ((uint32_t)f2b(b)<<16); }
__device__ __forceinline__ float lrelu(float e){ return e > 0.f ? e : 0.2f*e; }

// ---------------- W transpose+cast: Wt[c][k] = bf16(W[head][k][hid]) -------
__global__ __launch_bounds__(256) void k_transposeW(const float* __restrict__ W, u16* __restrict__ Wt){
  int i = blockIdx.x*256 + threadIdx.x;
  if (i >= FDIM*NFEATC) return;
  int c = i >> 7, k = i & 127;
  int head = c >> 5, hid = c & 31;
  Wt[c*NFEATC + k] = f2b(W[head*(NFEATC*NHIDC) + k*NHIDC + hid]);
}

// ---------------- W_out transpose: Wo_t[c][k] = W_out[k][c] ----------------
__global__ __launch_bounds__(256) void k_transposeWout(const float* __restrict__ W_out, float* __restrict__ Wo_t){
  int i = blockIdx.x*256 + threadIdx.x;
  if (i >= FDIM*NCLASSC) return;
  int c = i / FDIM, k = i % FDIM;
  Wo_t[i] = W_out[(size_t)k*NCLASSC + c];
}

// ---------------- GEMM1 via MFMA: h0 = x @ W  (bf16 out) -------------------
__global__ __launch_bounds__(256) void k_gemm1_mfma(const float* __restrict__ x, const u16* __restrict__ Wt,
                                                    u16* __restrict__ h0){
  int w = threadIdx.x >> 6, lane = threadIdx.x & 63;
  int nt = blockIdx.x;
  int m = lane & 15, q = lane >> 4;
  int row = nt*16 + m;
  int c0 = w*64;
  const float* xrow = x + (size_t)row*NFEATC;
  f32x4 acc0 = {0.f,0.f,0.f,0.f}, acc1 = {0.f,0.f,0.f,0.f};
  f32x4 acc2 = {0.f,0.f,0.f,0.f}, acc3 = {0.f,0.f,0.f,0.f};
  #pragma unroll
  for (int kk=0; kk<NFEATC; kk+=32){
    int ko = kk + q*8;
    float4 xa = *(const float4*)(xrow + ko);
    float4 xb = *(const float4*)(xrow + ko + 4);
    bf16x8 a;
    a[0]=(short)f2b(xa.x); a[1]=(short)f2b(xa.y); a[2]=(short)f2b(xa.z); a[3]=(short)f2b(xa.w);
    a[4]=(short)f2b(xb.x); a[5]=(short)f2b(xb.y); a[6]=(short)f2b(xb.z); a[7]=(short)f2b(xb.w);
    bf16x8 b0 = *(const bf16x8*)(Wt + (size_t)(c0 +  0 + m)*NFEATC + ko);
    bf16x8 b1 = *(const bf16x8*)(Wt + (size_t)(c0 + 16 + m)*NFEATC + ko);
    bf16x8 b2 = *(const bf16x8*)(Wt + (size_t)(c0 + 32 + m)*NFEATC + ko);
    bf16x8 b3 = *(const bf16x8*)(Wt + (size_t)(c0 + 48 + m)*NFEATC + ko);
    acc0 = __builtin_amdgcn_mfma_f32_16x16x32_bf16(a, b0, acc0, 0,0,0);
    acc1 = __builtin_amdgcn_mfma_f32_16x16x32_bf16(a, b1, acc1, 0,0,0);
    acc2 = __builtin_amdgcn_mfma_f32_16x16x32_bf16(a, b2, acc2, 0,0,0);
    acc3 = __builtin_amdgcn_mfma_f32_16x16x32_bf16(a, b3, acc3, 0,0,0);
  }
  #pragma unroll
  for (int r=0; r<4; r++){
    size_t base = (size_t)(nt*16 + q*4 + r)*FDIM + c0 + m;
    h0[base +  0] = f2b(acc0[r]);
    h0[base + 16] = f2b(acc1[r]);
    h0[base + 32] = f2b(acc2[r]);
    h0[base + 48] = f2b(acc3[r]);
  }
}

// ---------------- s,t per (node,head), bf16 --------------------------------
__global__ __launch_bounds__(256) void k_st(const u16* __restrict__ h0, const float* __restrict__ a_src,
                                            const float* __restrict__ a_dst, u16* __restrict__ s,
                                            u16* __restrict__ t_){
  int i = blockIdx.x*256 + threadIdx.x;
  if (i >= NN*NHEADSC) return;
  int n = i>>3, head = i&7;
  const u16* hp = h0 + (size_t)n*FDIM + head*NHIDC;
  const float* ap = a_src + head*NHIDC;
  const float* bp = a_dst + head*NHIDC;
  float ss=0.f, tt=0.f;
  #pragma unroll
  for (int j=0;j<NHIDC;j++){
    float h = b2f(hp[j]);
    ss = fmaf(h, ap[j], ss); tt = fmaf(h, bp[j], tt);
  }
  s[i]=f2b(ss); t_[i]=f2b(tt);
}

// ---------------- CSR build ------------------------------------------------
__global__ __launch_bounds__(256) void k_zero(int* __restrict__ p, int n){
  int i = blockIdx.x*256 + threadIdx.x;
  if (i < n) p[i] = 0;
}
__global__ __launch_bounds__(256) void k_count(const int* __restrict__ dst, int* __restrict__ counts){
  int e = blockIdx.x*256 + threadIdx.x;
  if (e < EE) atomicAdd(&counts[dst[e]], 1);
}
__global__ __launch_bounds__(256) void k_blocksum(const int* __restrict__ counts, int* __restrict__ bsum){
  __shared__ int wsum[4];
  int b = blockIdx.x, t = threadIdx.x;
  int i = b*256 + t;
  int v = (i < NN) ? counts[i] : 0;
  #pragma unroll
  for (int off=32; off; off>>=1) v += __shfl_xor(v, off);
  if ((t & 63) == 0) wsum[t>>6] = v;
  __syncthreads();
  if (t == 0) bsum[b] = wsum[0]+wsum[1]+wsum[2]+wsum[3];
}
__global__ __launch_bounds__(512) void k_scan_bsum(const int* __restrict__ bsum, int* __restrict__ boff){
  __shared__ int lds[512];
  int t = threadIdx.x;
  int v = (t < NBLK) ? bsum[t] : 0;
  lds[t] = v; __syncthreads();
  for (int off=1; off<512; off<<=1){
    int u = (t>=off) ? lds[t-off] : 0;
    __syncthreads();
    lds[t] += u;
    __syncthreads();
  }
  if (t < NBLK) boff[t] = lds[t] - v;
}
__global__ __launch_bounds__(256) void k_scan_final(const int* __restrict__ counts, const int* __restrict__ boff,
                                                    int* __restrict__ row_start){
  __shared__ int lds[256];
  int b = blockIdx.x, t = threadIdx.x;
  int i = b*256 + t;
  int v = (i < NN) ? counts[i] : 0;
  lds[t] = v; __syncthreads();
  for (int off=1; off<256; off<<=1){
    int u = (t>=off) ? lds[t-off] : 0;
    __syncthreads();
    lds[t] += u;
    __syncthreads();
  }
  if (i < NN) row_start[i] = boff[b] + lds[t] - v;
  if (b == 0 && t == 0) row_start[NN] = EE;
}
__global__ __launch_bounds__(256) void k_scatter(const int* __restrict__ src, const int* __restrict__ dst,
                                                 const int* __restrict__ row_start, int* __restrict__ fill,
                                                 int* __restrict__ csr_src){
  int e = blockIdx.x*256 + threadIdx.x;
  if (e >= EE) return;
  int d = dst[e];
  int pos = row_start[d] + atomicAdd(&fill[d], 1);
  csr_src[pos] = src[e];
}

// ---------------- attention, all 8 heads: p_all (bf16) + 1/denom (fp16) ----
__global__ __launch_bounds__(256) void k_att(const u16* __restrict__ s, const u16* __restrict__ t_,
                                             const int* __restrict__ row_start, const int* __restrict__ csr_src,
                                             u16* __restrict__ p_all, __half* __restrict__ scale){
  int i = blockIdx.x*256 + threadIdx.x;
  if (i >= NN*NHEADSC) return;
  int n = i>>3, head = i&7;
  int beg = row_start[n], end = row_start[n+1];
  float tn = b2f(t_[i]);
  float d0=0.f,d1=0.f,d2=0.f,d3=0.f;
  int pos = beg;
  for (; pos+4<=end; pos+=4){
    int u0=csr_src[pos], u1=csr_src[pos+1], u2=csr_src[pos+2], u3=csr_src[pos+3];
    float e0=lrelu(b2f(s[u0*NHEADSC+head])+tn);
    float e1=lrelu(b2f(s[u1*NHEADSC+head])+tn);
    float e2=lrelu(b2f(s[u2*NHEADSC+head])+tn);
    float e3=lrelu(b2f(s[u3*NHEADSC+head])+tn);
    u16 p0=f2b(__expf(e0)), p1=f2b(__expf(e1)), p2=f2b(__expf(e2)), p3=f2b(__expf(e3));
    p_all[(size_t)(pos+0)*NHEADSC+head]=p0;
    p_all[(size_t)(pos+1)*NHEADSC+head]=p1;
    p_all[(size_t)(pos+2)*NHEADSC+head]=p2;
    p_all[(size_t)(pos+3)*NHEADSC+head]=p3;
    d0+=b2f(p0); d1+=b2f(p1); d2+=b2f(p2); d3+=b2f(p3);
  }
  for (; pos<end; pos++){
    int u = csr_src[pos];
    float e = lrelu(b2f(s[u*NHEADSC+head])+tn);
    u16 pb = f2b(__expf(e));
    p_all[(size_t)pos*NHEADSC+head]=pb;
    d0 += b2f(pb);
  }
  scale[i] = __float2half(1.0f/(((d0+d1)+(d2+d3)) + 1e-16f));
}

// ---------------- channel-split hop kernels --------------------------------
// Two sequential launches per hop (pass=0: ch 0-127, pass=1: ch 128-255).
// Per-pass gather footprint = 25.6 MB (L3-resident). Quarter-wave groups:
// 16 lanes/edge, 8 ch/lane -> one dwordx4 instr gathers 4 random 256B rows.
// Masked-uniform 8-edge iterations + 1-ahead index prefetch; p_all addressed
// linearly in pos (NO second gather on the critical path — round-3 lesson).
#define ACC8(p, g) \
  a0=fmaf(p,lof(g.x),a0); a1=fmaf(p,hif(g.x),a1); \
  a2=fmaf(p,lof(g.y),a2); a3=fmaf(p,hif(g.y),a3); \
  a4=fmaf(p,lof(g.z),a4); a5=fmaf(p,hif(g.z),a5); \
  a6=fmaf(p,lof(g.w),a6); a7=fmaf(p,hif(g.w),a7);

__global__ __launch_bounds__(256) void k_hop1_split(const u16* __restrict__ h0, const u16* __restrict__ p_all,
                                                    const __half* __restrict__ scale, const int* __restrict__ row_start,
                                                    const int* __restrict__ csr_src, u16* __restrict__ featA,
                                                    int pass){
  int wv = threadIdx.x >> 6, l = threadIdx.x & 63;
  int n = blockIdx.x*4 + wv;
  int g = l >> 4, il = l & 15;
  int cg = pass*128 + il*8;
  int head = cg >> 5;                       // pass*4 + (il>>2)
  float sc_ = __half2float(scale[n*NHEADSC + head]);
  int beg = row_start[n], end = row_start[n+1];
  float a0=0.f,a1=0.f,a2=0.f,a3=0.f,a4=0.f,a5=0.f,a6=0.f,a7=0.f;
  int e0,e1;
  {
    int v0=beg+g, v1=beg+4+g;
    int c0=csr_src[v0<EE?v0:EE-1], c1=csr_src[v1<EE?v1:EE-1];
    e0 = v0<end?c0:n; e1 = v1<end?c1:n;
  }
  for (int pos=beg; pos<end; pos+=8){
    int w0=pos+8+g, w1=pos+12+g;
    int c0=csr_src[w0<EE?w0:EE-1], c1=csr_src[w1<EE?w1:EE-1];
    int q0 = (pos+g  )<EE ? (pos+g  ) : EE-1;
    int q1 = (pos+4+g)<EE ? (pos+4+g) : EE-1;
    float pv0 = (pos+g   < end) ? b2f(p_all[(size_t)q0*NHEADSC+head]) : 0.f;
    float pv1 = (pos+4+g < end) ? b2f(p_all[(size_t)q1*NHEADSC+head]) : 0.f;
    uint4 g0 = *(const uint4*)(h0 + (size_t)e0*FDIM + cg);
    uint4 g1 = *(const uint4*)(h0 + (size_t)e1*FDIM + cg);
    ACC8(pv0,g0) ACC8(pv1,g1)
    e0 = w0<end?c0:n; e1 = w1<end?c1:n;
  }
  a0 += __shfl_xor(a0,16); a1 += __shfl_xor(a1,16); a2 += __shfl_xor(a2,16); a3 += __shfl_xor(a3,16);
  a4 += __shfl_xor(a4,16); a5 += __shfl_xor(a5,16); a6 += __shfl_xor(a6,16); a7 += __shfl_xor(a7,16);
  a0 += __shfl_xor(a0,32); a1 += __shfl_xor(a1,32); a2 += __shfl_xor(a2,32); a3 += __shfl_xor(a3,32);
  a4 += __shfl_xor(a4,32); a5 += __shfl_xor(a5,32); a6 += __shfl_xor(a6,32); a7 += __shfl_xor(a7,32);
  if (l < 16){
    uint4 hu = *(const uint4*)(h0 + (size_t)n*FDIM + cg);
    float r0 = 0.9f*sc_*a0 + 0.1f*lof(hu.x);
    float r1 = 0.9f*sc_*a1 + 0.1f*hif(hu.x);
    float r2 = 0.9f*sc_*a2 + 0.1f*lof(hu.y);
    float r3 = 0.9f*sc_*a3 + 0.1f*hif(hu.y);
    float r4 = 0.9f*sc_*a4 + 0.1f*lof(hu.z);
    float r5 = 0.9f*sc_*a5 + 0.1f*hif(hu.z);
    float r6 = 0.9f*sc_*a6 + 0.1f*lof(hu.w);
    float r7 = 0.9f*sc_*a7 + 0.1f*hif(hu.w);
    uint4 o;
    o.x = pack2(r0,r1); o.y = pack2(r2,r3); o.z = pack2(r4,r5); o.w = pack2(r6,r7);
    *(uint4*)(featA + (size_t)n*FDIM + cg) = o;
  }
}

// hop2 split: same gather structure on featA; epilogue computes the partial
// GEMM2 over this pass's 128 k's and accumulates into out0 (pass1 adds).
__global__ __launch_bounds__(256) void k_hop2_split(const u16* __restrict__ featA, const u16* __restrict__ h0,
                                                    const u16* __restrict__ p_all, const __half* __restrict__ scale,
                                                    const int* __restrict__ row_start, const int* __restrict__ csr_src,
                                                    const float* __restrict__ Wo_t, float* __restrict__ out0,
                                                    int pass){
  __shared__ __align__(16) float hs[4][132];
  int wv = threadIdx.x >> 6, l = threadIdx.x & 63;
  int n = blockIdx.x*4 + wv;
  int g = l >> 4, il = l & 15;
  int cg = pass*128 + il*8;
  int head = cg >> 5;
  float sc_ = __half2float(scale[n*NHEADSC + head]);
  int beg = row_start[n], end = row_start[n+1];
  float a0=0.f,a1=0.f,a2=0.f,a3=0.f,a4=0.f,a5=0.f,a6=0.f,a7=0.f;
  int e0,e1;
  {
    int v0=beg+g, v1=beg+4+g;
    int c0=csr_src[v0<EE?v0:EE-1], c1=csr_src[v1<EE?v1:EE-1];
    e0 = v0<end?c0:n; e1 = v1<end?c1:n;
  }
  for (int pos=beg; pos<end; pos+=8){
    int w0=pos+8+g, w1=pos+12+g;
    int c0=csr_src[w0<EE?w0:EE-1], c1=csr_src[w1<EE?w1:EE-1];
    int q0 = (pos+g  )<EE ? (pos+g  ) : EE-1;
    int q1 = (pos+4+g)<EE ? (pos+4+g) : EE-1;
    float pv0 = (pos+g   < end) ? b2f(p_all[(size_t)q0*NHEADSC+head]) : 0.f;
    float pv1 = (pos+4+g < end) ? b2f(p_all[(size_t)q1*NHEADSC+head]) : 0.f;
    uint4 g0 = *(const uint4*)(featA + (size_t)e0*FDIM + cg);
    uint4 g1 = *(const uint4*)(featA + (size_t)e1*FDIM + cg);
    ACC8(pv0,g0) ACC8(pv1,g1)
    e0 = w0<end?c0:n; e1 = w1<end?c1:n;
  }
  a0 += __shfl_xor(a0,16); a1 += __shfl_xor(a1,16); a2 += __shfl_xor(a2,16); a3 += __shfl_xor(a3,16);
  a4 += __shfl_xor(a4,16); a5 += __shfl_xor(a5,16); a6 += __shfl_xor(a6,16); a7 += __shfl_xor(a7,16);
  a0 += __shfl_xor(a0,32); a1 += __shfl_xor(a1,32); a2 += __shfl_xor(a2,32); a3 += __shfl_xor(a3,32);
  a4 += __shfl_xor(a4,32); a5 += __shfl_xor(a5,32); a6 += __shfl_xor(a6,32); a7 += __shfl_xor(a7,32);
  if (l < 16){
    uint4 hu = *(const uint4*)(h0 + (size_t)n*FDIM + cg);
    float r0 = 0.9f*sc_*a0 + 0.1f*lof(hu.x);
    float r1 = 0.9f*sc_*a1 + 0.1f*hif(hu.x);
    float r2 = 0.9f*sc_*a2 + 0.1f*lof(hu.y);
    float r3 = 0.9f*sc_*a3 + 0.1f*hif(hu.y);
    float r4 = 0.9f*sc_*a4 + 0.1f*lof(hu.z);
    float r5 = 0.9f*sc_*a5 + 0.1f*hif(hu.z);
    float r6 = 0.9f*sc_*a6 + 0.1f*lof(hu.w);
    float r7 = 0.9f*sc_*a7 + 0.1f*hif(hu.w);
    float4 ha, hb;
    ha.x = r0 > 0.f ? r0 : (__expf(r0)-1.0f);
    ha.y = r1 > 0.f ? r1 : (__expf(r1)-1.0f);
    ha.z = r2 > 0.f ? r2 : (__expf(r2)-1.0f);
    ha.w = r3 > 0.f ? r3 : (__expf(r3)-1.0f);
    hb.x = r4 > 0.f ? r4 : (__expf(r4)-1.0f);
    hb.y = r5 > 0.f ? r5 : (__expf(r5)-1.0f);
    hb.z = r6 > 0.f ? r6 : (__expf(r6)-1.0f);
    hb.w = r7 > 0.f ? r7 : (__expf(r7)-1.0f);
    *(float4*)&hs[wv][il*8  ] = ha;
    *(float4*)&hs[wv][il*8+4] = hb;
  }
  __syncthreads();
  int t = threadIdx.x;
  if (t < 4*NCLASSC){
    int node = t/NCLASSC, c = t%NCLASSC;
    const float* hv = hs[node];
    const float* wt = Wo_t + (size_t)c*FDIM + pass*128;
    float o0=0.f,o1=0.f,o2=0.f,o3=0.f;
    #pragma unroll 8
    for (int k=0;k<128;k+=4){
      float4 h4 = *(const float4*)(hv + k);
      float4 w4 = *(const float4*)(wt + k);
      o0=fmaf(h4.x,w4.x,o0); o1=fmaf(h4.y,w4.y,o1);
      o2=fmaf(h4.z,w4.z,o2); o3=fmaf(h4.w,w4.w,o3);
    }
    float o = (o0+o1)+(o2+o3);
    size_t oi = (size_t)(blockIdx.x*4+node)*NCLASSC + c;
    if (pass == 0) out0[oi] = o;
    else           out0[oi] += o;
  }
}

// ---------------- output-layer s,t -----------------------------------------
__global__ __launch_bounds__(256) void k_st_out(const float* __restrict__ out0, const float* __restrict__ a_s,
                                                const float* __restrict__ a_d, float* __restrict__ s,
                                                float* __restrict__ t_){
  int n = blockIdx.x*256 + threadIdx.x;
  if (n >= NN) return;
  const float* r = out0 + (size_t)n*NCLASSC;
  float ss=0.f, tt=0.f;
  for (int c=0;c<NCLASSC;c++){ float v=r[c]; ss=fmaf(v,a_s[c],ss); tt=fmaf(v,a_d[c],tt); }
  s[n]=ss; t_[n]=tt;
}

// ---------------- output-layer attention: p (fp32), unroll x4 --------------
__global__ __launch_bounds__(256) void k_att_out(const float* __restrict__ s, const float* __restrict__ t_,
                                                 const int* __restrict__ row_start, const int* __restrict__ csr_src,
                                                 float* __restrict__ p_out, float* __restrict__ scale_out){
  int n = blockIdx.x*256 + threadIdx.x;
  if (n >= NN) return;
  int beg = row_start[n], end = row_start[n+1];
  float tn = t_[n];
  float d0=0.f,d1=0.f,d2=0.f,d3=0.f;
  int pos = beg;
  for (; pos+4<=end; pos+=4){
    int u0=csr_src[pos], u1=csr_src[pos+1], u2=csr_src[pos+2], u3=csr_src[pos+3];
    float p0=__expf(lrelu(s[u0]+tn));
    float p1=__expf(lrelu(s[u1]+tn));
    float p2=__expf(lrelu(s[u2]+tn));
    float p3=__expf(lrelu(s[u3]+tn));
    p_out[pos]=p0; p_out[pos+1]=p1; p_out[pos+2]=p2; p_out[pos+3]=p3;
    d0+=p0; d1+=p1; d2+=p2; d3+=p3;
  }
  for (; pos<end; pos++){
    float p = __expf(lrelu(s[csr_src[pos]]+tn));
    p_out[pos] = p;
    d0 += p;
  }
  scale_out[n] = 1.0f/(((d0+d1)+(d2+d3)) + 1e-16f);
}

// ---------------- output-layer hop 1, unroll x4 ----------------------------
__global__ __launch_bounds__(64) void k_hop1_out(const float* __restrict__ out0, const float* __restrict__ p_out,
                                                 const float* __restrict__ scale_out, const int* __restrict__ row_start,
                                                 const int* __restrict__ csr_src, u16* __restrict__ outA){
  int n = blockIdx.x, t = threadIdx.x;
  float sc_ = scale_out[n];
  int beg = row_start[n], end = row_start[n+1];
  int tc = (t < NCLASSC) ? t : 0;
  float a0=0.f,a1=0.f,a2=0.f,a3=0.f;
  int pos = beg;
  for (; pos+4<=end; pos+=4){
    int u0=csr_src[pos], u1=csr_src[pos+1], u2=csr_src[pos+2], u3=csr_src[pos+3];
    float p0=p_out[pos], p1=p_out[pos+1], p2=p_out[pos+2], p3=p_out[pos+3];
    float f0=out0[(size_t)u0*NCLASSC+tc];
    float f1=out0[(size_t)u1*NCLASSC+tc];
    float f2=out0[(size_t)u2*NCLASSC+tc];
    float f3=out0[(size_t)u3*NCLASSC+tc];
    a0=fmaf(p0,f0,a0); a1=fmaf(p1,f1,a1); a2=fmaf(p2,f2,a2); a3=fmaf(p3,f3,a3);
  }
  for (; pos<end; pos++){
    a0=fmaf(p_out[pos], out0[(size_t)csr_src[pos]*NCLASSC+tc], a0);
  }
  if (t < NCLASSC){
    float res = 0.9f*sc_*((a0+a1)+(a2+a3)) + 0.1f*out0[(size_t)n*NCLASSC + t];
    outA[(size_t)n*NCLASSC + t] = f2b(res);
  }
}

// ---------------- output-layer hop 2 + elu + log_softmax, unroll x4 --------
__global__ __launch_bounds__(64) void k_hop2_out_final(const u16* __restrict__ outA, const float* __restrict__ out0,
                                                       const float* __restrict__ p_out, const float* __restrict__ scale_out,
                                                       const int* __restrict__ row_start, const int* __restrict__ csr_src,
                                                       float* __restrict__ out){
  int n = blockIdx.x, t = threadIdx.x;
  float sc_ = scale_out[n];
  int beg = row_start[n], end = row_start[n+1];
  int tc = (t < NCLASSC) ? t : 0;
  float a0=0.f,a1=0.f,a2=0.f,a3=0.f;
  int pos = beg;
  for (; pos+4<=end; pos+=4){
    int u0=csr_src[pos], u1=csr_src[pos+1], u2=csr_src[pos+2], u3=csr_src[pos+3];
    float p0=p_out[pos], p1=p_out[pos+1], p2=p_out[pos+2], p3=p_out[pos+3];
    float f0=b2f(outA[(size_t)u0*NCLASSC+tc]);
    float f1=b2f(outA[(size_t)u1*NCLASSC+tc]);
    float f2=b2f(outA[(size_t)u2*NCLASSC+tc]);
    float f3=b2f(outA[(size_t)u3*NCLASSC+tc]);
    a0=fmaf(p0,f0,a0); a1=fmaf(p1,f1,a1); a2=fmaf(p2,f2,a2); a3=fmaf(p3,f3,a3);
  }
  for (; pos<end; pos++){
    a0=fmaf(p_out[pos], b2f(outA[(size_t)csr_src[pos]*NCLASSC+tc]), a0);
  }
  float v = -1e30f;
  if (t < NCLASSC){
    float res = 0.9f*sc_*((a0+a1)+(a2+a3)) + 0.1f*out0[(size_t)n*NCLASSC + t];
    v = res > 0.f ? res : (__expf(res)-1.0f);
  }
  float m = v;
  #pragma unroll
  for (int off=32; off; off>>=1) m = fmaxf(m, __shfl_xor(m, off));
  float ex = (t < NCLASSC) ? __expf(v - m) : 0.f;
  float ssum = ex;
  #pragma unroll
  for (int off=32; off; off>>=1) ssum += __shfl_xor(ssum, off);
  if (t < NCLASSC) out[(size_t)n*NCLASSC + t] = v - m - __logf(ssum);
}

extern "C" void kernel_launch(void* const* d_in, const int* in_sizes, int n_in,
                              void* d_out, int out_size, void* d_ws, size_t ws_size,
                              hipStream_t stream){
  const float* x        = (const float*)d_in[0];
  const int*   ei       = (const int*)d_in[1];
  const float* W        = (const float*)d_in[2];
  const float* a_src    = (const float*)d_in[3];
  const float* a_dst    = (const float*)d_in[4];
  const float* W_out    = (const float*)d_in[5];
  const float* a_src_o  = (const float*)d_in[6];
  const float* a_dst_o  = (const float*)d_in[7];
  float* out            = (float*)d_out;
  const int* e_src = ei;
  const int* e_dst = ei + EE;

  // ---- workspace: ~156.1 MB (< 156.87 MB proven safe) ----
  char* ws = (char*)d_ws;
  size_t off = 0;
  auto alloc = [&](size_t bytes)->char*{ char* p = ws + off; off += (bytes + 255) & ~(size_t)255; return p; };

  u16*    h0        = (u16*)   alloc((size_t)NN*FDIM*2);      // 51.2 MB
  u16*    featA     = (u16*)   alloc((size_t)NN*FDIM*2);      // 51.2 MB (outA aliases after phase 3)
  float*  out0      = (float*) alloc((size_t)NN*NCLASSC*4);   // 16 MB
  int*    csr_src   = (int*)   alloc((size_t)EE*4);           // 6.4 MB
  int*    row_start = (int*)   alloc((size_t)(NN+1)*4);       // 0.4 MB
  char*   regS      =          alloc((size_t)NN*NHEADSC*2*2); // 3.2 MB: s,t bf16; phase-4 fp32 smalls
  u16*    p_all     = (u16*)   alloc((size_t)EE*NHEADSC*2);   // 25.6 MB (fp32 p_out aliased later)
  __half* scale     = (__half*)alloc((size_t)NN*NHEADSC*2);   // 1.6 MB
  int*    counts    = (int*)   alloc((size_t)NN*4);           // 0.4 MB
  int*    bsum      = (int*)   alloc((size_t)NBLK*4);
  int*    boff      = (int*)   alloc((size_t)NBLK*4);
  u16*    Wt        = (u16*)   alloc((size_t)FDIM*NFEATC*2);  // 64 KB
  float*  Wo_t      = (float*) alloc((size_t)FDIM*NCLASSC*4); // 40 KB

  u16*   s         = (u16*)regS;                       // phase 1-3
  u16*   t_        = (u16*)(regS + (size_t)NN*NHEADSC*2);
  float* s_out     = (float*)regS;                     // phase 4 (s,t dead)
  float* t_out     = s_out + NN;
  float* scale_out = t_out + NN;
  u16*   outA      = (u16*)featA;                      // phase 4 (featA dead)
  float* p_out     = (float*)p_all;                    // phase 4 (p_all dead)

  // phase 1: feature transform (MFMA) + per-head s,t
  k_transposeW<<<(FDIM*NFEATC+255)/256, 256, 0, stream>>>(W, Wt);
  k_transposeWout<<<(FDIM*NCLASSC+255)/256, 256, 0, stream>>>(W_out, Wo_t);
  k_gemm1_mfma<<<NN/16, 256, 0, stream>>>(x, Wt, h0);
  k_st<<<(NN*NHEADSC+255)/256, 256, 0, stream>>>(h0, a_src, a_dst, s, t_);

  // phase 2: CSR build (hierarchical scan)
  k_zero<<<(NN+255)/256, 256, 0, stream>>>(counts, NN);
  k_count<<<(EE+255)/256, 256, 0, stream>>>(e_dst, counts);
  k_blocksum<<<NBLK, 256, 0, stream>>>(counts, bsum);
  k_scan_bsum<<<1, 512, 0, stream>>>(bsum, boff);
  k_scan_final<<<NBLK, 256, 0, stream>>>(counts, boff, row_start);
  k_zero<<<(NN+255)/256, 256, 0, stream>>>(counts, NN);
  k_scatter<<<(EE+255)/256, 256, 0, stream>>>(e_src, e_dst, row_start, counts, csr_src);

  // phase 3: attention, then channel-split hops (2 sequential passes each)
  k_att<<<(NN*NHEADSC+255)/256, 256, 0, stream>>>(s, t_, row_start, csr_src, p_all, scale);
  k_hop1_split<<<NN/4, 256, 0, stream>>>(h0, p_all, scale, row_start, csr_src, featA, 0);
  k_hop1_split<<<NN/4, 256, 0, stream>>>(h0, p_all, scale, row_start, csr_src, featA, 1);
  k_hop2_split<<<NN/4, 256, 0, stream>>>(featA, h0, p_all, scale, row_start, csr_src, Wo_t, out0, 0);
  k_hop2_split<<<NN/4, 256, 0, stream>>>(featA, h0, p_all, scale, row_start, csr_src, Wo_t, out0, 1);

  // phase 4: output layer (p precomputed fp32, aliased into p_all)
  k_st_out<<<(NN+255)/256, 256, 0, stream>>>(out0, a_src_o, a_dst_o, s_out, t_out);
  k_att_out<<<(NN+255)/256, 256, 0, stream>>>(s_out, t_out, row_start, csr_src, p_out, scale_out);
  k_hop1_out<<<NN, 64, 0, stream>>>(out0, p_out, scale_out, row_start, csr_src, outA);
  k_hop2_out_final<<<NN, 64, 0, stream>>>(outA, out0, p_out, scale_out, row_start, csr_src, out);
}

// Round 5
// 954.704 us; speedup vs baseline: 1.2407x; 1.2407x over previous
//
#include <hip/hip_runtime.h>
#include <hip/hip_fp16.h>
#include <stdint.h>

#define NN      100000
#define EE      1600000
#define NFEATC  128
#define NHIDC   32
#define NHEADSC 8
#define NCLASSC 40
#define FDIM    256     // NHEADS*NHID
#define NBLK    ((NN+255)/256)   // 391

typedef unsigned short u16;
typedef __attribute__((ext_vector_type(8))) short bf16x8;
typedef __attribute__((ext_vector_type(4))) float f32x4;

__device__ __forceinline__ float b2f(u16 u){ union{uint32_t i; float f;} v; v.i=((uint32_t)u)<<16; return v.f; }
__device__ __forceinline__ float lof(uint32_t u){ union{uint32_t i; float f;} v; v.i=u<<16; return v.f; }
__device__ __forceinline__ float hif(uint32_t u){ union{uint32_t i; float f;} v; v.i=u&0xFFFF0000u; return v.f; }
__device__ __forceinline__ u16 f2b(float f){ union{float f; uint32_t i;} v; v.f=f; uint32_t x=v.i; return (u16)((x + 0x7FFFu + ((x>>16)&1u))>>16); }
__device__ __forceinline__ uint32_t pack2(float a, float b){ return (uint32_t)f2b(a) | ((uint32_t)f2b(b)<<16); }
__device__ __forceinline__ float lrelu(float e){ return e > 0.f ? e : 0.2f*e; }

// ---------------- W transpose+cast: Wt[c][k] = bf16(W[head][k][hid]) -------
__global__ __launch_bounds__(256) void k_transposeW(const float* __restrict__ W, u16* __restrict__ Wt){
  int i = blockIdx.x*256 + threadIdx.x;
  if (i >= FDIM*NFEATC) return;
  int c = i >> 7, k = i & 127;
  int head = c >> 5, hid = c & 31;
  Wt[c*NFEATC + k] = f2b(W[head*(NFEATC*NHIDC) + k*NHIDC + hid]);
}

// ---------------- GEMM1 via MFMA: h0 = x @ W  (bf16 out) -------------------
__global__ __launch_bounds__(256) void k_gemm1_mfma(const float* __restrict__ x, const u16* __restrict__ Wt,
                                                    u16* __restrict__ h0){
  int w = threadIdx.x >> 6, lane = threadIdx.x & 63;
  int nt = blockIdx.x;
  int m = lane & 15, q = lane >> 4;
  int row = nt*16 + m;
  int c0 = w*64;
  const float* xrow = x + (size_t)row*NFEATC;
  f32x4 acc0 = {0.f,0.f,0.f,0.f}, acc1 = {0.f,0.f,0.f,0.f};
  f32x4 acc2 = {0.f,0.f,0.f,0.f}, acc3 = {0.f,0.f,0.f,0.f};
  #pragma unroll
  for (int kk=0; kk<NFEATC; kk+=32){
    int ko = kk + q*8;
    float4 xa = *(const float4*)(xrow + ko);
    float4 xb = *(const float4*)(xrow + ko + 4);
    bf16x8 a;
    a[0]=(short)f2b(xa.x); a[1]=(short)f2b(xa.y); a[2]=(short)f2b(xa.z); a[3]=(short)f2b(xa.w);
    a[4]=(short)f2b(xb.x); a[5]=(short)f2b(xb.y); a[6]=(short)f2b(xb.z); a[7]=(short)f2b(xb.w);
    bf16x8 b0 = *(const bf16x8*)(Wt + (size_t)(c0 +  0 + m)*NFEATC + ko);
    bf16x8 b1 = *(const bf16x8*)(Wt + (size_t)(c0 + 16 + m)*NFEATC + ko);
    bf16x8 b2 = *(const bf16x8*)(Wt + (size_t)(c0 + 32 + m)*NFEATC + ko);
    bf16x8 b3 = *(const bf16x8*)(Wt + (size_t)(c0 + 48 + m)*NFEATC + ko);
    acc0 = __builtin_amdgcn_mfma_f32_16x16x32_bf16(a, b0, acc0, 0,0,0);
    acc1 = __builtin_amdgcn_mfma_f32_16x16x32_bf16(a, b1, acc1, 0,0,0);
    acc2 = __builtin_amdgcn_mfma_f32_16x16x32_bf16(a, b2, acc2, 0,0,0);
    acc3 = __builtin_amdgcn_mfma_f32_16x16x32_bf16(a, b3, acc3, 0,0,0);
  }
  #pragma unroll
  for (int r=0; r<4; r++){
    size_t base = (size_t)(nt*16 + q*4 + r)*FDIM + c0 + m;
    h0[base +  0] = f2b(acc0[r]);
    h0[base + 16] = f2b(acc1[r]);
    h0[base + 32] = f2b(acc2[r]);
    h0[base + 48] = f2b(acc3[r]);
  }
}

// ---------------- s,t per (node,head), bf16 --------------------------------
__global__ __launch_bounds__(256) void k_st(const u16* __restrict__ h0, const float* __restrict__ a_src,
                                            const float* __restrict__ a_dst, u16* __restrict__ s,
                                            u16* __restrict__ t_){
  int i = blockIdx.x*256 + threadIdx.x;
  if (i >= NN*NHEADSC) return;
  int n = i>>3, head = i&7;
  const u16* hp = h0 + (size_t)n*FDIM + head*NHIDC;
  const float* ap = a_src + head*NHIDC;
  const float* bp = a_dst + head*NHIDC;
  float ss=0.f, tt=0.f;
  #pragma unroll
  for (int j=0;j<NHIDC;j++){
    float h = b2f(hp[j]);
    ss = fmaf(h, ap[j], ss); tt = fmaf(h, bp[j], tt);
  }
  s[i]=f2b(ss); t_[i]=f2b(tt);
}

// ---------------- CSR build ------------------------------------------------
__global__ __launch_bounds__(256) void k_zero(int* __restrict__ p, int n){
  int i = blockIdx.x*256 + threadIdx.x;
  if (i < n) p[i] = 0;
}
__global__ __launch_bounds__(256) void k_count(const int* __restrict__ dst, int* __restrict__ counts){
  int e = blockIdx.x*256 + threadIdx.x;
  if (e < EE) atomicAdd(&counts[dst[e]], 1);
}
__global__ __launch_bounds__(256) void k_blocksum(const int* __restrict__ counts, int* __restrict__ bsum){
  __shared__ int wsum[4];
  int b = blockIdx.x, t = threadIdx.x;
  int i = b*256 + t;
  int v = (i < NN) ? counts[i] : 0;
  #pragma unroll
  for (int off=32; off; off>>=1) v += __shfl_xor(v, off);
  if ((t & 63) == 0) wsum[t>>6] = v;
  __syncthreads();
  if (t == 0) bsum[b] = wsum[0]+wsum[1]+wsum[2]+wsum[3];
}
__global__ __launch_bounds__(512) void k_scan_bsum(const int* __restrict__ bsum, int* __restrict__ boff){
  __shared__ int lds[512];
  int t = threadIdx.x;
  int v = (t < NBLK) ? bsum[t] : 0;
  lds[t] = v; __syncthreads();
  for (int off=1; off<512; off<<=1){
    int u = (t>=off) ? lds[t-off] : 0;
    __syncthreads();
    lds[t] += u;
    __syncthreads();
  }
  if (t < NBLK) boff[t] = lds[t] - v;
}
__global__ __launch_bounds__(256) void k_scan_final(const int* __restrict__ counts, const int* __restrict__ boff,
                                                    int* __restrict__ row_start){
  __shared__ int lds[256];
  int b = blockIdx.x, t = threadIdx.x;
  int i = b*256 + t;
  int v = (i < NN) ? counts[i] : 0;
  lds[t] = v; __syncthreads();
  for (int off=1; off<256; off<<=1){
    int u = (t>=off) ? lds[t-off] : 0;
    __syncthreads();
    lds[t] += u;
    __syncthreads();
  }
  if (i < NN) row_start[i] = boff[b] + lds[t] - v;
  if (b == 0 && t == 0) row_start[NN] = EE;
}
__global__ __launch_bounds__(256) void k_scatter(const int* __restrict__ src, const int* __restrict__ dst,
                                                 const int* __restrict__ row_start, int* __restrict__ fill,
                                                 int* __restrict__ csr_src){
  int e = blockIdx.x*256 + threadIdx.x;
  if (e >= EE) return;
  int d = dst[e];
  int pos = row_start[d] + atomicAdd(&fill[d], 1);
  csr_src[pos] = src[e];
}

// ---------------- attention, all 8 heads: p_all (bf16) + 1/denom (fp16) ----
__global__ __launch_bounds__(256) void k_att(const u16* __restrict__ s, const u16* __restrict__ t_,
                                             const int* __restrict__ row_start, const int* __restrict__ csr_src,
                                             u16* __restrict__ p_all, __half* __restrict__ scale){
  int i = blockIdx.x*256 + threadIdx.x;
  if (i >= NN*NHEADSC) return;
  int n = i>>3, head = i&7;
  int beg = row_start[n], end = row_start[n+1];
  float tn = b2f(t_[i]);
  float d0=0.f,d1=0.f,d2=0.f,d3=0.f;
  int pos = beg;
  for (; pos+4<=end; pos+=4){
    int u0=csr_src[pos], u1=csr_src[pos+1], u2=csr_src[pos+2], u3=csr_src[pos+3];
    float e0=lrelu(b2f(s[u0*NHEADSC+head])+tn);
    float e1=lrelu(b2f(s[u1*NHEADSC+head])+tn);
    float e2=lrelu(b2f(s[u2*NHEADSC+head])+tn);
    float e3=lrelu(b2f(s[u3*NHEADSC+head])+tn);
    u16 p0=f2b(__expf(e0)), p1=f2b(__expf(e1)), p2=f2b(__expf(e2)), p3=f2b(__expf(e3));
    p_all[(size_t)(pos+0)*NHEADSC+head]=p0;
    p_all[(size_t)(pos+1)*NHEADSC+head]=p1;
    p_all[(size_t)(pos+2)*NHEADSC+head]=p2;
    p_all[(size_t)(pos+3)*NHEADSC+head]=p3;
    d0+=b2f(p0); d1+=b2f(p1); d2+=b2f(p2); d3+=b2f(p3);
  }
  for (; pos<end; pos++){
    int u = csr_src[pos];
    float e = lrelu(b2f(s[u*NHEADSC+head])+tn);
    u16 pb = f2b(__expf(e));
    p_all[(size_t)pos*NHEADSC+head]=pb;
    d0 += b2f(pb);
  }
  scale[i] = __float2half(1.0f/(((d0+d1)+(d2+d3)) + 1e-16f));
}

// ---------------- hop kernels: half-wave edge pairs, 8 ch/lane -------------
// 16-edge main stage keeps 8 uint4 gathers (8 KB/wave) in flight before any
// consumption (r4 lesson: per-wave MLP is the lever; VGPR 32 was starving it),
// falling through to the proven 8/2/1-edge stages from round 1.
#define ACC8(p, g) \
  a0=fmaf(p,lof(g.x),a0); a1=fmaf(p,hif(g.x),a1); \
  a2=fmaf(p,lof(g.y),a2); a3=fmaf(p,hif(g.y),a3); \
  a4=fmaf(p,lof(g.z),a4); a5=fmaf(p,hif(g.z),a5); \
  a6=fmaf(p,lof(g.w),a6); a7=fmaf(p,hif(g.w),a7);

__global__ __launch_bounds__(256) void k_hop1(const u16* __restrict__ h0, const u16* __restrict__ p_all,
                                              const __half* __restrict__ scale, const int* __restrict__ row_start,
                                              const int* __restrict__ csr_src, u16* __restrict__ featA){
  int wv = threadIdx.x >> 6, l = threadIdx.x & 63;
  int n = blockIdx.x*4 + wv;
  int half = l >> 5, sl = l & 31;
  int cg = 8*sl;
  int head = sl >> 2;
  float tn_sc = __half2float(scale[n*NHEADSC + head]);
  int beg = row_start[n], end = row_start[n+1];
  float a0=0.f,a1=0.f,a2=0.f,a3=0.f,a4=0.f,a5=0.f,a6=0.f,a7=0.f;
  int pos = beg;
  for (; pos+16<=end; pos+=16){
    int e0=csr_src[pos+ 0+half], e1=csr_src[pos+ 2+half], e2=csr_src[pos+ 4+half], e3=csr_src[pos+ 6+half];
    int e4=csr_src[pos+ 8+half], e5=csr_src[pos+10+half], e6=csr_src[pos+12+half], e7=csr_src[pos+14+half];
    float p0=b2f(p_all[(size_t)(pos+ 0+half)*NHEADSC+head]);
    float p1=b2f(p_all[(size_t)(pos+ 2+half)*NHEADSC+head]);
    float p2=b2f(p_all[(size_t)(pos+ 4+half)*NHEADSC+head]);
    float p3=b2f(p_all[(size_t)(pos+ 6+half)*NHEADSC+head]);
    float p4=b2f(p_all[(size_t)(pos+ 8+half)*NHEADSC+head]);
    float p5=b2f(p_all[(size_t)(pos+10+half)*NHEADSC+head]);
    float p6=b2f(p_all[(size_t)(pos+12+half)*NHEADSC+head]);
    float p7=b2f(p_all[(size_t)(pos+14+half)*NHEADSC+head]);
    uint4 g0 = *(const uint4*)(h0 + (size_t)e0*FDIM + cg);
    uint4 g1 = *(const uint4*)(h0 + (size_t)e1*FDIM + cg);
    uint4 g2 = *(const uint4*)(h0 + (size_t)e2*FDIM + cg);
    uint4 g3 = *(const uint4*)(h0 + (size_t)e3*FDIM + cg);
    uint4 g4 = *(const uint4*)(h0 + (size_t)e4*FDIM + cg);
    uint4 g5 = *(const uint4*)(h0 + (size_t)e5*FDIM + cg);
    uint4 g6 = *(const uint4*)(h0 + (size_t)e6*FDIM + cg);
    uint4 g7 = *(const uint4*)(h0 + (size_t)e7*FDIM + cg);
    ACC8(p0,g0) ACC8(p1,g1) ACC8(p2,g2) ACC8(p3,g3)
    ACC8(p4,g4) ACC8(p5,g5) ACC8(p6,g6) ACC8(p7,g7)
  }
  for (; pos+8<=end; pos+=8){
    int e0=csr_src[pos+0+half], e1=csr_src[pos+2+half], e2=csr_src[pos+4+half], e3=csr_src[pos+6+half];
    float p0=b2f(p_all[(size_t)(pos+0+half)*NHEADSC+head]);
    float p1=b2f(p_all[(size_t)(pos+2+half)*NHEADSC+head]);
    float p2=b2f(p_all[(size_t)(pos+4+half)*NHEADSC+head]);
    float p3=b2f(p_all[(size_t)(pos+6+half)*NHEADSC+head]);
    uint4 g0 = *(const uint4*)(h0 + (size_t)e0*FDIM + cg);
    uint4 g1 = *(const uint4*)(h0 + (size_t)e1*FDIM + cg);
    uint4 g2 = *(const uint4*)(h0 + (size_t)e2*FDIM + cg);
    uint4 g3 = *(const uint4*)(h0 + (size_t)e3*FDIM + cg);
    ACC8(p0,g0) ACC8(p1,g1) ACC8(p2,g2) ACC8(p3,g3)
  }
  for (; pos+2<=end; pos+=2){
    int e = csr_src[pos+half];
    float p = b2f(p_all[(size_t)(pos+half)*NHEADSC+head]);
    uint4 g = *(const uint4*)(h0 + (size_t)e*FDIM + cg);
    ACC8(p, g)
  }
  if (pos < end && half == 0){
    int e = csr_src[pos];
    float p = b2f(p_all[(size_t)pos*NHEADSC+head]);
    uint4 g = *(const uint4*)(h0 + (size_t)e*FDIM + cg);
    ACC8(p, g)
  }
  a0 += __shfl_xor(a0, 32); a1 += __shfl_xor(a1, 32);
  a2 += __shfl_xor(a2, 32); a3 += __shfl_xor(a3, 32);
  a4 += __shfl_xor(a4, 32); a5 += __shfl_xor(a5, 32);
  a6 += __shfl_xor(a6, 32); a7 += __shfl_xor(a7, 32);
  if (half == 0){
    uint4 hu = *(const uint4*)(h0 + (size_t)n*FDIM + cg);
    float r0 = 0.9f*tn_sc*a0 + 0.1f*lof(hu.x);
    float r1 = 0.9f*tn_sc*a1 + 0.1f*hif(hu.x);
    float r2 = 0.9f*tn_sc*a2 + 0.1f*lof(hu.y);
    float r3 = 0.9f*tn_sc*a3 + 0.1f*hif(hu.y);
    float r4 = 0.9f*tn_sc*a4 + 0.1f*lof(hu.z);
    float r5 = 0.9f*tn_sc*a5 + 0.1f*hif(hu.z);
    float r6 = 0.9f*tn_sc*a6 + 0.1f*lof(hu.w);
    float r7 = 0.9f*tn_sc*a7 + 0.1f*hif(hu.w);
    uint4 o;
    o.x = pack2(r0,r1); o.y = pack2(r2,r3); o.z = pack2(r4,r5); o.w = pack2(r6,r7);
    *(uint4*)(featA + (size_t)n*FDIM + cg) = o;
  }
}

// ---------------- hop2 full row + elu + GEMM2 ------------------------------
__global__ __launch_bounds__(256) void k_hop2(const u16* __restrict__ featA, const u16* __restrict__ h0,
                                              const u16* __restrict__ p_all, const __half* __restrict__ scale,
                                              const int* __restrict__ row_start, const int* __restrict__ csr_src,
                                              const float* __restrict__ W_out, float* __restrict__ out0){
  __shared__ float hs[4][FDIM+4];
  int wv = threadIdx.x >> 6, l = threadIdx.x & 63;
  int n = blockIdx.x*4 + wv;
  int half = l >> 5, sl = l & 31;
  int cg = 8*sl;
  int head = sl >> 2;
  float tn_sc = __half2float(scale[n*NHEADSC + head]);
  int beg = row_start[n], end = row_start[n+1];
  float a0=0.f,a1=0.f,a2=0.f,a3=0.f,a4=0.f,a5=0.f,a6=0.f,a7=0.f;
  int pos = beg;
  for (; pos+16<=end; pos+=16){
    int e0=csr_src[pos+ 0+half], e1=csr_src[pos+ 2+half], e2=csr_src[pos+ 4+half], e3=csr_src[pos+ 6+half];
    int e4=csr_src[pos+ 8+half], e5=csr_src[pos+10+half], e6=csr_src[pos+12+half], e7=csr_src[pos+14+half];
    float p0=b2f(p_all[(size_t)(pos+ 0+half)*NHEADSC+head]);
    float p1=b2f(p_all[(size_t)(pos+ 2+half)*NHEADSC+head]);
    float p2=b2f(p_all[(size_t)(pos+ 4+half)*NHEADSC+head]);
    float p3=b2f(p_all[(size_t)(pos+ 6+half)*NHEADSC+head]);
    float p4=b2f(p_all[(size_t)(pos+ 8+half)*NHEADSC+head]);
    float p5=b2f(p_all[(size_t)(pos+10+half)*NHEADSC+head]);
    float p6=b2f(p_all[(size_t)(pos+12+half)*NHEADSC+head]);
    float p7=b2f(p_all[(size_t)(pos+14+half)*NHEADSC+head]);
    uint4 g0 = *(const uint4*)(featA + (size_t)e0*FDIM + cg);
    uint4 g1 = *(const uint4*)(featA + (size_t)e1*FDIM + cg);
    uint4 g2 = *(const uint4*)(featA + (size_t)e2*FDIM + cg);
    uint4 g3 = *(const uint4*)(featA + (size_t)e3*FDIM + cg);
    uint4 g4 = *(const uint4*)(featA + (size_t)e4*FDIM + cg);
    uint4 g5 = *(const uint4*)(featA + (size_t)e5*FDIM + cg);
    uint4 g6 = *(const uint4*)(featA + (size_t)e6*FDIM + cg);
    uint4 g7 = *(const uint4*)(featA + (size_t)e7*FDIM + cg);
    ACC8(p0,g0) ACC8(p1,g1) ACC8(p2,g2) ACC8(p3,g3)
    ACC8(p4,g4) ACC8(p5,g5) ACC8(p6,g6) ACC8(p7,g7)
  }
  for (; pos+8<=end; pos+=8){
    int e0=csr_src[pos+0+half], e1=csr_src[pos+2+half], e2=csr_src[pos+4+half], e3=csr_src[pos+6+half];
    float p0=b2f(p_all[(size_t)(pos+0+half)*NHEADSC+head]);
    float p1=b2f(p_all[(size_t)(pos+2+half)*NHEADSC+head]);
    float p2=b2f(p_all[(size_t)(pos+4+half)*NHEADSC+head]);
    float p3=b2f(p_all[(size_t)(pos+6+half)*NHEADSC+head]);
    uint4 g0 = *(const uint4*)(featA + (size_t)e0*FDIM + cg);
    uint4 g1 = *(const uint4*)(featA + (size_t)e1*FDIM + cg);
    uint4 g2 = *(const uint4*)(featA + (size_t)e2*FDIM + cg);
    uint4 g3 = *(const uint4*)(featA + (size_t)e3*FDIM + cg);
    ACC8(p0,g0) ACC8(p1,g1) ACC8(p2,g2) ACC8(p3,g3)
  }
  for (; pos+2<=end; pos+=2){
    int e = csr_src[pos+half];
    float p = b2f(p_all[(size_t)(pos+half)*NHEADSC+head]);
    uint4 g = *(const uint4*)(featA + (size_t)e*FDIM + cg);
    ACC8(p, g)
  }
  if (pos < end && half == 0){
    int e = csr_src[pos];
    float p = b2f(p_all[(size_t)pos*NHEADSC+head]);
    uint4 g = *(const uint4*)(featA + (size_t)e*FDIM + cg);
    ACC8(p, g)
  }
  a0 += __shfl_xor(a0, 32); a1 += __shfl_xor(a1, 32);
  a2 += __shfl_xor(a2, 32); a3 += __shfl_xor(a3, 32);
  a4 += __shfl_xor(a4, 32); a5 += __shfl_xor(a5, 32);
  a6 += __shfl_xor(a6, 32); a7 += __shfl_xor(a7, 32);
  if (half == 0){
    uint4 hu = *(const uint4*)(h0 + (size_t)n*FDIM + cg);
    float r0 = 0.9f*tn_sc*a0 + 0.1f*lof(hu.x);
    float r1 = 0.9f*tn_sc*a1 + 0.1f*hif(hu.x);
    float r2 = 0.9f*tn_sc*a2 + 0.1f*lof(hu.y);
    float r3 = 0.9f*tn_sc*a3 + 0.1f*hif(hu.y);
    float r4 = 0.9f*tn_sc*a4 + 0.1f*lof(hu.z);
    float r5 = 0.9f*tn_sc*a5 + 0.1f*hif(hu.z);
    float r6 = 0.9f*tn_sc*a6 + 0.1f*lof(hu.w);
    float r7 = 0.9f*tn_sc*a7 + 0.1f*hif(hu.w);
    hs[wv][cg  ] = r0 > 0.f ? r0 : (__expf(r0)-1.0f);
    hs[wv][cg+1] = r1 > 0.f ? r1 : (__expf(r1)-1.0f);
    hs[wv][cg+2] = r2 > 0.f ? r2 : (__expf(r2)-1.0f);
    hs[wv][cg+3] = r3 > 0.f ? r3 : (__expf(r3)-1.0f);
    hs[wv][cg+4] = r4 > 0.f ? r4 : (__expf(r4)-1.0f);
    hs[wv][cg+5] = r5 > 0.f ? r5 : (__expf(r5)-1.0f);
    hs[wv][cg+6] = r6 > 0.f ? r6 : (__expf(r6)-1.0f);
    hs[wv][cg+7] = r7 > 0.f ? r7 : (__expf(r7)-1.0f);
  }
  __syncthreads();
  int t = threadIdx.x;
  if (t < 4*NCLASSC){
    int node = t/NCLASSC, c = t%NCLASSC;
    const float* hv = hs[node];
    const float* wp = W_out + c;
    float o = 0.f;
    #pragma unroll 8
    for (int k=0;k<FDIM;k++) o = fmaf(hv[k], wp[(size_t)k*NCLASSC], o);
    out0[(size_t)(blockIdx.x*4+node)*NCLASSC + c] = o;
  }
}

// ---------------- output-layer s,t -----------------------------------------
__global__ __launch_bounds__(256) void k_st_out(const float* __restrict__ out0, const float* __restrict__ a_s,
                                                const float* __restrict__ a_d, float* __restrict__ s,
                                                float* __restrict__ t_){
  int n = blockIdx.x*256 + threadIdx.x;
  if (n >= NN) return;
  const float* r = out0 + (size_t)n*NCLASSC;
  float ss=0.f, tt=0.f;
  for (int c=0;c<NCLASSC;c++){ float v=r[c]; ss=fmaf(v,a_s[c],ss); tt=fmaf(v,a_d[c],tt); }
  s[n]=ss; t_[n]=tt;
}

// ---------------- output-layer attention: p (fp32), unroll x4 --------------
__global__ __launch_bounds__(256) void k_att_out(const float* __restrict__ s, const float* __restrict__ t_,
                                                 const int* __restrict__ row_start, const int* __restrict__ csr_src,
                                                 float* __restrict__ p_out, float* __restrict__ scale_out){
  int n = blockIdx.x*256 + threadIdx.x;
  if (n >= NN) return;
  int beg = row_start[n], end = row_start[n+1];
  float tn = t_[n];
  float d0=0.f,d1=0.f,d2=0.f,d3=0.f;
  int pos = beg;
  for (; pos+4<=end; pos+=4){
    int u0=csr_src[pos], u1=csr_src[pos+1], u2=csr_src[pos+2], u3=csr_src[pos+3];
    float p0=__expf(lrelu(s[u0]+tn));
    float p1=__expf(lrelu(s[u1]+tn));
    float p2=__expf(lrelu(s[u2]+tn));
    float p3=__expf(lrelu(s[u3]+tn));
    p_out[pos]=p0; p_out[pos+1]=p1; p_out[pos+2]=p2; p_out[pos+3]=p3;
    d0+=p0; d1+=p1; d2+=p2; d3+=p3;
  }
  for (; pos<end; pos++){
    float p = __expf(lrelu(s[csr_src[pos]]+tn));
    p_out[pos] = p;
    d0 += p;
  }
  scale_out[n] = 1.0f/(((d0+d1)+(d2+d3)) + 1e-16f);
}

// ---------------- output-layer hop 1, unroll x4 ----------------------------
__global__ __launch_bounds__(64) void k_hop1_out(const float* __restrict__ out0, const float* __restrict__ p_out,
                                                 const float* __restrict__ scale_out, const int* __restrict__ row_start,
                                                 const int* __restrict__ csr_src, u16* __restrict__ outA){
  int n = blockIdx.x, t = threadIdx.x;
  float sc_ = scale_out[n];
  int beg = row_start[n], end = row_start[n+1];
  int tc = (t < NCLASSC) ? t : 0;
  float a0=0.f,a1=0.f,a2=0.f,a3=0.f;
  int pos = beg;
  for (; pos+4<=end; pos+=4){
    int u0=csr_src[pos], u1=csr_src[pos+1], u2=csr_src[pos+2], u3=csr_src[pos+3];
    float p0=p_out[pos], p1=p_out[pos+1], p2=p_out[pos+2], p3=p_out[pos+3];
    float f0=out0[(size_t)u0*NCLASSC+tc];
    float f1=out0[(size_t)u1*NCLASSC+tc];
    float f2=out0[(size_t)u2*NCLASSC+tc];
    float f3=out0[(size_t)u3*NCLASSC+tc];
    a0=fmaf(p0,f0,a0); a1=fmaf(p1,f1,a1); a2=fmaf(p2,f2,a2); a3=fmaf(p3,f3,a3);
  }
  for (; pos<end; pos++){
    a0=fmaf(p_out[pos], out0[(size_t)csr_src[pos]*NCLASSC+tc], a0);
  }
  if (t < NCLASSC){
    float res = 0.9f*sc_*((a0+a1)+(a2+a3)) + 0.1f*out0[(size_t)n*NCLASSC + t];
    outA[(size_t)n*NCLASSC + t] = f2b(res);
  }
}

// ---------------- output-layer hop 2 + elu + log_softmax, unroll x4 --------
__global__ __launch_bounds__(64) void k_hop2_out_final(const u16* __restrict__ outA, const float* __restrict__ out0,
                                                       const float* __restrict__ p_out, const float* __restrict__ scale_out,
                                                       const int* __restrict__ row_start, const int* __restrict__ csr_src,
                                                       float* __restrict__ out){
  int n = blockIdx.x, t = threadIdx.x;
  float sc_ = scale_out[n];
  int beg = row_start[n], end = row_start[n+1];
  int tc = (t < NCLASSC) ? t : 0;
  float a0=0.f,a1=0.f,a2=0.f,a3=0.f;
  int pos = beg;
  for (; pos+4<=end; pos+=4){
    int u0=csr_src[pos], u1=csr_src[pos+1], u2=csr_src[pos+2], u3=csr_src[pos+3];
    float p0=p_out[pos], p1=p_out[pos+1], p2=p_out[pos+2], p3=p_out[pos+3];
    float f0=b2f(outA[(size_t)u0*NCLASSC+tc]);
    float f1=b2f(outA[(size_t)u1*NCLASSC+tc]);
    float f2=b2f(outA[(size_t)u2*NCLASSC+tc]);
    float f3=b2f(outA[(size_t)u3*NCLASSC+tc]);
    a0=fmaf(p0,f0,a0); a1=fmaf(p1,f1,a1); a2=fmaf(p2,f2,a2); a3=fmaf(p3,f3,a3);
  }
  for (; pos<end; pos++){
    a0=fmaf(p_out[pos], b2f(outA[(size_t)csr_src[pos]*NCLASSC+tc]), a0);
  }
  float v = -1e30f;
  if (t < NCLASSC){
    float res = 0.9f*sc_*((a0+a1)+(a2+a3)) + 0.1f*out0[(size_t)n*NCLASSC + t];
    v = res > 0.f ? res : (__expf(res)-1.0f);
  }
  float m = v;
  #pragma unroll
  for (int off=32; off; off>>=1) m = fmaxf(m, __shfl_xor(m, off));
  float ex = (t < NCLASSC) ? __expf(v - m) : 0.f;
  float ssum = ex;
  #pragma unroll
  for (int off=32; off; off>>=1) ssum += __shfl_xor(ssum, off);
  if (t < NCLASSC) out[(size_t)n*NCLASSC + t] = v - m - __logf(ssum);
}

extern "C" void kernel_launch(void* const* d_in, const int* in_sizes, int n_in,
                              void* d_out, int out_size, void* d_ws, size_t ws_size,
                              hipStream_t stream){
  const float* x        = (const float*)d_in[0];
  const int*   ei       = (const int*)d_in[1];
  const float* W        = (const float*)d_in[2];
  const float* a_src    = (const float*)d_in[3];
  const float* a_dst    = (const float*)d_in[4];
  const float* W_out    = (const float*)d_in[5];
  const float* a_src_o  = (const float*)d_in[6];
  const float* a_dst_o  = (const float*)d_in[7];
  float* out            = (float*)d_out;
  const int* e_src = ei;
  const int* e_dst = ei + EE;

  // ---- workspace: ~156.1 MB (< 156.87 MB proven safe) ----
  char* ws = (char*)d_ws;
  size_t off = 0;
  auto alloc = [&](size_t bytes)->char*{ char* p = ws + off; off += (bytes + 255) & ~(size_t)255; return p; };

  u16*    h0        = (u16*)   alloc((size_t)NN*FDIM*2);      // 51.2 MB
  u16*    featA     = (u16*)   alloc((size_t)NN*FDIM*2);      // 51.2 MB (outA aliases after phase 3)
  float*  out0      = (float*) alloc((size_t)NN*NCLASSC*4);   // 16 MB
  int*    csr_src   = (int*)   alloc((size_t)EE*4);           // 6.4 MB
  int*    row_start = (int*)   alloc((size_t)(NN+1)*4);       // 0.4 MB
  char*   regS      =          alloc((size_t)NN*NHEADSC*2*2); // 3.2 MB: s,t then phase-4 smalls
  u16*    p_all     = (u16*)   alloc((size_t)EE*NHEADSC*2);   // 25.6 MB (fp32 p_out aliased later)
  __half* scale     = (__half*)alloc((size_t)NN*NHEADSC*2);   // 1.6 MB
  int*    counts    = (int*)   alloc((size_t)NN*4);           // 0.4 MB
  int*    bsum      = (int*)   alloc((size_t)NBLK*4);
  int*    boff      = (int*)   alloc((size_t)NBLK*4);
  u16*    Wt        = (u16*)   alloc((size_t)FDIM*NFEATC*2);  // 64 KB

  u16*   s         = (u16*)regS;                       // phase 1-3a
  u16*   t_        = (u16*)(regS + (size_t)NN*NHEADSC*2);
  float* s_out     = (float*)regS;                     // phase 4 (s,t dead)
  float* t_out     = s_out + NN;
  float* scale_out = t_out + NN;
  u16*   outA      = (u16*)featA;                      // phase 4 (featA dead)
  float* p_out     = (float*)p_all;                    // phase 4 (p_all dead)

  // phase 1: feature transform (MFMA) + per-head s,t
  k_transposeW<<<(FDIM*NFEATC+255)/256, 256, 0, stream>>>(W, Wt);
  k_gemm1_mfma<<<NN/16, 256, 0, stream>>>(x, Wt, h0);
  k_st<<<(NN*NHEADSC+255)/256, 256, 0, stream>>>(h0, a_src, a_dst, s, t_);

  // phase 2: CSR build (hierarchical scan)
  k_zero<<<(NN+255)/256, 256, 0, stream>>>(counts, NN);
  k_count<<<(EE+255)/256, 256, 0, stream>>>(e_dst, counts);
  k_blocksum<<<NBLK, 256, 0, stream>>>(counts, bsum);
  k_scan_bsum<<<1, 512, 0, stream>>>(bsum, boff);
  k_scan_final<<<NBLK, 256, 0, stream>>>(counts, boff, row_start);
  k_zero<<<(NN+255)/256, 256, 0, stream>>>(counts, NN);
  k_scatter<<<(EE+255)/256, 256, 0, stream>>>(e_src, e_dst, row_start, counts, csr_src);

  // phase 3: attention pass, then full-row hop1 + hop2(+GEMM2)
  k_att<<<(NN*NHEADSC+255)/256, 256, 0, stream>>>(s, t_, row_start, csr_src, p_all, scale);
  k_hop1<<<NN/4, 256, 0, stream>>>(h0, p_all, scale, row_start, csr_src, featA);
  k_hop2<<<NN/4, 256, 0, stream>>>(featA, h0, p_all, scale, row_start, csr_src, W_out, out0);

  // phase 4: output layer (p precomputed fp32, aliased into p_all)
  k_st_out<<<(NN+255)/256, 256, 0, stream>>>(out0, a_src_o, a_dst_o, s_out, t_out);
  k_att_out<<<(NN+255)/256, 256, 0, stream>>>(s_out, t_out, row_start, csr_src, p_out, scale_out);
  k_hop1_out<<<NN, 64, 0, stream>>>(out0, p_out, scale_out, row_start, csr_src, outA);
  k_hop2_out_final<<<NN, 64, 0, stream>>>(outA, out0, p_out, scale_out, row_start, csr_src, out);
}

// Round 6
// 848.095 us; speedup vs baseline: 1.3966x; 1.1257x over previous
//
#include <hip/hip_runtime.h>
#include <hip/hip_fp16.h>
#include <stdint.h>

#define NN      100000
#define EE      1600000
#define NFEATC  128
#define NHIDC   32
#define NHEADSC 8
#define NCLASSC 40
#define FDIM    256     // NHEADS*NHID
#define NBLK    ((NN+255)/256)   // 391

typedef unsigned short u16;
typedef __attribute__((ext_vector_type(8))) short bf16x8;
typedef __attribute__((ext_vector_type(4))) float f32x4;

__device__ __forceinline__ float b2f(u16 u){ union{uint32_t i; float f;} v; v.i=((uint32_t)u)<<16; return v.f; }
__device__ __forceinline__ float lof(uint32_t u){ union{uint32_t i; float f;} v; v.i=u<<16; return v.f; }
__device__ __forceinline__ float hif(uint32_t u){ union{uint32_t i; float f;} v; v.i=u&0xFFFF0000u; return v.f; }
__device__ __forceinline__ u16 f2b(float f){ union{float f; uint32_t i;} v; v.f=f; uint32_t x=v.i; return (u16)((x + 0x7FFFu + ((x>>16)&1u))>>16); }
__device__ __forceinline__ uint32_t pack2(float a, float b){ return (uint32_t)f2b(a) | ((uint32_t)f2b(b)<<16); }
__device__ __forceinline__ float lrelu(float e){ return e > 0.f ? e : 0.2f*e; }

// ---------------- W transpose+cast: Wt[c][k] = bf16(W[head][k][hid]) -------
__global__ __launch_bounds__(256) void k_transposeW(const float* __restrict__ W, u16* __restrict__ Wt){
  int i = blockIdx.x*256 + threadIdx.x;
  if (i >= FDIM*NFEATC) return;
  int c = i >> 7, k = i & 127;
  int head = c >> 5, hid = c & 31;
  Wt[c*NFEATC + k] = f2b(W[head*(NFEATC*NHIDC) + k*NHIDC + hid]);
}

// ---------------- GEMM1 via MFMA: h0 = x @ W  (bf16 out) -------------------
__global__ __launch_bounds__(256) void k_gemm1_mfma(const float* __restrict__ x, const u16* __restrict__ Wt,
                                                    u16* __restrict__ h0){
  int w = threadIdx.x >> 6, lane = threadIdx.x & 63;
  int nt = blockIdx.x;
  int m = lane & 15, q = lane >> 4;
  int row = nt*16 + m;
  int c0 = w*64;
  const float* xrow = x + (size_t)row*NFEATC;
  f32x4 acc0 = {0.f,0.f,0.f,0.f}, acc1 = {0.f,0.f,0.f,0.f};
  f32x4 acc2 = {0.f,0.f,0.f,0.f}, acc3 = {0.f,0.f,0.f,0.f};
  #pragma unroll
  for (int kk=0; kk<NFEATC; kk+=32){
    int ko = kk + q*8;
    float4 xa = *(const float4*)(xrow + ko);
    float4 xb = *(const float4*)(xrow + ko + 4);
    bf16x8 a;
    a[0]=(short)f2b(xa.x); a[1]=(short)f2b(xa.y); a[2]=(short)f2b(xa.z); a[3]=(short)f2b(xa.w);
    a[4]=(short)f2b(xb.x); a[5]=(short)f2b(xb.y); a[6]=(short)f2b(xb.z); a[7]=(short)f2b(xb.w);
    bf16x8 b0 = *(const bf16x8*)(Wt + (size_t)(c0 +  0 + m)*NFEATC + ko);
    bf16x8 b1 = *(const bf16x8*)(Wt + (size_t)(c0 + 16 + m)*NFEATC + ko);
    bf16x8 b2 = *(const bf16x8*)(Wt + (size_t)(c0 + 32 + m)*NFEATC + ko);
    bf16x8 b3 = *(const bf16x8*)(Wt + (size_t)(c0 + 48 + m)*NFEATC + ko);
    acc0 = __builtin_amdgcn_mfma_f32_16x16x32_bf16(a, b0, acc0, 0,0,0);
    acc1 = __builtin_amdgcn_mfma_f32_16x16x32_bf16(a, b1, acc1, 0,0,0);
    acc2 = __builtin_amdgcn_mfma_f32_16x16x32_bf16(a, b2, acc2, 0,0,0);
    acc3 = __builtin_amdgcn_mfma_f32_16x16x32_bf16(a, b3, acc3, 0,0,0);
  }
  #pragma unroll
  for (int r=0; r<4; r++){
    size_t base = (size_t)(nt*16 + q*4 + r)*FDIM + c0 + m;
    h0[base +  0] = f2b(acc0[r]);
    h0[base + 16] = f2b(acc1[r]);
    h0[base + 32] = f2b(acc2[r]);
    h0[base + 48] = f2b(acc3[r]);
  }
}

// ---------------- s,t per (node,head), bf16, vectorized loads --------------
__global__ __launch_bounds__(256) void k_st(const u16* __restrict__ h0, const float* __restrict__ a_src,
                                            const float* __restrict__ a_dst, u16* __restrict__ s,
                                            u16* __restrict__ t_){
  int i = blockIdx.x*256 + threadIdx.x;
  if (i >= NN*NHEADSC) return;
  int n = i>>3, head = i&7;
  const uint4*  hp = (const uint4*)(h0 + (size_t)n*FDIM + head*NHIDC);
  const float4* ap = (const float4*)(a_src + head*NHIDC);
  const float4* bp = (const float4*)(a_dst + head*NHIDC);
  float ss=0.f, tt=0.f;
  #pragma unroll
  for (int j=0;j<4;j++){
    uint4 hv = hp[j];
    float4 a0v=ap[2*j], a1v=ap[2*j+1], b0v=bp[2*j], b1v=bp[2*j+1];
    float h0f=lof(hv.x), h1f=hif(hv.x), h2f=lof(hv.y), h3f=hif(hv.y);
    float h4f=lof(hv.z), h5f=hif(hv.z), h6f=lof(hv.w), h7f=hif(hv.w);
    ss=fmaf(h0f,a0v.x,ss); tt=fmaf(h0f,b0v.x,tt);
    ss=fmaf(h1f,a0v.y,ss); tt=fmaf(h1f,b0v.y,tt);
    ss=fmaf(h2f,a0v.z,ss); tt=fmaf(h2f,b0v.z,tt);
    ss=fmaf(h3f,a0v.w,ss); tt=fmaf(h3f,b0v.w,tt);
    ss=fmaf(h4f,a1v.x,ss); tt=fmaf(h4f,b1v.x,tt);
    ss=fmaf(h5f,a1v.y,ss); tt=fmaf(h5f,b1v.y,tt);
    ss=fmaf(h6f,a1v.z,ss); tt=fmaf(h6f,b1v.z,tt);
    ss=fmaf(h7f,a1v.w,ss); tt=fmaf(h7f,b1v.w,tt);
  }
  s[i]=f2b(ss); t_[i]=f2b(tt);
}

// ---------------- CSR build ------------------------------------------------
__global__ __launch_bounds__(256) void k_zero(int* __restrict__ p, int n){
  int i = blockIdx.x*256 + threadIdx.x;
  if (i < n) p[i] = 0;
}
__global__ __launch_bounds__(256) void k_count(const int* __restrict__ dst, int* __restrict__ counts){
  int e = blockIdx.x*256 + threadIdx.x;
  if (e < EE) atomicAdd(&counts[dst[e]], 1);
}
__global__ __launch_bounds__(256) void k_blocksum(const int* __restrict__ counts, int* __restrict__ bsum){
  __shared__ int wsum[4];
  int b = blockIdx.x, t = threadIdx.x;
  int i = b*256 + t;
  int v = (i < NN) ? counts[i] : 0;
  #pragma unroll
  for (int off=32; off; off>>=1) v += __shfl_xor(v, off);
  if ((t & 63) == 0) wsum[t>>6] = v;
  __syncthreads();
  if (t == 0) bsum[b] = wsum[0]+wsum[1]+wsum[2]+wsum[3];
}
__global__ __launch_bounds__(512) void k_scan_bsum(const int* __restrict__ bsum, int* __restrict__ boff){
  __shared__ int lds[512];
  int t = threadIdx.x;
  int v = (t < NBLK) ? bsum[t] : 0;
  lds[t] = v; __syncthreads();
  for (int off=1; off<512; off<<=1){
    int u = (t>=off) ? lds[t-off] : 0;
    __syncthreads();
    lds[t] += u;
    __syncthreads();
  }
  if (t < NBLK) boff[t] = lds[t] - v;
}
__global__ __launch_bounds__(256) void k_scan_final(const int* __restrict__ counts, const int* __restrict__ boff,
                                                    int* __restrict__ row_start){
  __shared__ int lds[256];
  int b = blockIdx.x, t = threadIdx.x;
  int i = b*256 + t;
  int v = (i < NN) ? counts[i] : 0;
  lds[t] = v; __syncthreads();
  for (int off=1; off<256; off<<=1){
    int u = (t>=off) ? lds[t-off] : 0;
    __syncthreads();
    lds[t] += u;
    __syncthreads();
  }
  if (i < NN) row_start[i] = boff[b] + lds[t] - v;
  if (b == 0 && t == 0) row_start[NN] = EE;
}
__global__ __launch_bounds__(256) void k_scatter(const int* __restrict__ src, const int* __restrict__ dst,
                                                 const int* __restrict__ row_start, int* __restrict__ fill,
                                                 int* __restrict__ csr_src){
  int e = blockIdx.x*256 + threadIdx.x;
  if (e >= EE) return;
  int d = dst[e];
  int pos = row_start[d] + atomicAdd(&fill[d], 1);
  csr_src[pos] = src[e];
}

// ---------------- attention, all 8 heads: p_all (bf16) + 1/denom (fp16) ----
__global__ __launch_bounds__(256) void k_att(const u16* __restrict__ s, const u16* __restrict__ t_,
                                             const int* __restrict__ row_start, const int* __restrict__ csr_src,
                                             u16* __restrict__ p_all, __half* __restrict__ scale){
  int i = blockIdx.x*256 + threadIdx.x;
  if (i >= NN*NHEADSC) return;
  int n = i>>3, head = i&7;
  int beg = row_start[n], end = row_start[n+1];
  float tn = b2f(t_[i]);
  float d0=0.f,d1=0.f,d2=0.f,d3=0.f;
  int pos = beg;
  for (; pos+4<=end; pos+=4){
    int u0=csr_src[pos], u1=csr_src[pos+1], u2=csr_src[pos+2], u3=csr_src[pos+3];
    float e0=lrelu(b2f(s[u0*NHEADSC+head])+tn);
    float e1=lrelu(b2f(s[u1*NHEADSC+head])+tn);
    float e2=lrelu(b2f(s[u2*NHEADSC+head])+tn);
    float e3=lrelu(b2f(s[u3*NHEADSC+head])+tn);
    u16 p0=f2b(__expf(e0)), p1=f2b(__expf(e1)), p2=f2b(__expf(e2)), p3=f2b(__expf(e3));
    p_all[(size_t)(pos+0)*NHEADSC+head]=p0;
    p_all[(size_t)(pos+1)*NHEADSC+head]=p1;
    p_all[(size_t)(pos+2)*NHEADSC+head]=p2;
    p_all[(size_t)(pos+3)*NHEADSC+head]=p3;
    d0+=b2f(p0); d1+=b2f(p1); d2+=b2f(p2); d3+=b2f(p3);
  }
  for (; pos<end; pos++){
    int u = csr_src[pos];
    float e = lrelu(b2f(s[u*NHEADSC+head])+tn);
    u16 pb = f2b(__expf(e));
    p_all[(size_t)pos*NHEADSC+head]=pb;
    d0 += b2f(pb);
  }
  scale[i] = __float2half(1.0f/(((d0+d1)+(d2+d3)) + 1e-16f));
}

// ---------------- hop kernels: half-wave edge pairs, 8 ch/lane (r1 best) ---
#define ACC8(p, g) \
  a0=fmaf(p,lof(g.x),a0); a1=fmaf(p,hif(g.x),a1); \
  a2=fmaf(p,lof(g.y),a2); a3=fmaf(p,hif(g.y),a3); \
  a4=fmaf(p,lof(g.z),a4); a5=fmaf(p,hif(g.z),a5); \
  a6=fmaf(p,lof(g.w),a6); a7=fmaf(p,hif(g.w),a7);

__global__ __launch_bounds__(256) void k_hop1(const u16* __restrict__ h0, const u16* __restrict__ p_all,
                                              const __half* __restrict__ scale, const int* __restrict__ row_start,
                                              const int* __restrict__ csr_src, u16* __restrict__ featA){
  int wv = threadIdx.x >> 6, l = threadIdx.x & 63;
  int n = blockIdx.x*4 + wv;
  int half = l >> 5, sl = l & 31;
  int cg = 8*sl;
  int head = sl >> 2;
  float sc_ = __half2float(scale[n*NHEADSC + head]);
  int beg = row_start[n], end = row_start[n+1];
  float a0=0.f,a1=0.f,a2=0.f,a3=0.f,a4=0.f,a5=0.f,a6=0.f,a7=0.f;
  int pos = beg;
  for (; pos+8<=end; pos+=8){
    int e0=csr_src[pos+0+half], e1=csr_src[pos+2+half], e2=csr_src[pos+4+half], e3=csr_src[pos+6+half];
    float p0=b2f(p_all[(size_t)(pos+0+half)*NHEADSC+head]);
    float p1=b2f(p_all[(size_t)(pos+2+half)*NHEADSC+head]);
    float p2=b2f(p_all[(size_t)(pos+4+half)*NHEADSC+head]);
    float p3=b2f(p_all[(size_t)(pos+6+half)*NHEADSC+head]);
    uint4 g0 = *(const uint4*)(h0 + (size_t)e0*FDIM + cg);
    uint4 g1 = *(const uint4*)(h0 + (size_t)e1*FDIM + cg);
    uint4 g2 = *(const uint4*)(h0 + (size_t)e2*FDIM + cg);
    uint4 g3 = *(const uint4*)(h0 + (size_t)e3*FDIM + cg);
    ACC8(p0,g0) ACC8(p1,g1) ACC8(p2,g2) ACC8(p3,g3)
  }
  for (; pos+2<=end; pos+=2){
    int e = csr_src[pos+half];
    float p = b2f(p_all[(size_t)(pos+half)*NHEADSC+head]);
    uint4 g = *(const uint4*)(h0 + (size_t)e*FDIM + cg);
    ACC8(p, g)
  }
  if (pos < end && half == 0){
    int e = csr_src[pos];
    float p = b2f(p_all[(size_t)pos*NHEADSC+head]);
    uint4 g = *(const uint4*)(h0 + (size_t)e*FDIM + cg);
    ACC8(p, g)
  }
  a0 += __shfl_xor(a0, 32); a1 += __shfl_xor(a1, 32);
  a2 += __shfl_xor(a2, 32); a3 += __shfl_xor(a3, 32);
  a4 += __shfl_xor(a4, 32); a5 += __shfl_xor(a5, 32);
  a6 += __shfl_xor(a6, 32); a7 += __shfl_xor(a7, 32);
  if (half == 0){
    uint4 hu = *(const uint4*)(h0 + (size_t)n*FDIM + cg);
    float r0 = 0.9f*sc_*a0 + 0.1f*lof(hu.x);
    float r1 = 0.9f*sc_*a1 + 0.1f*hif(hu.x);
    float r2 = 0.9f*sc_*a2 + 0.1f*lof(hu.y);
    float r3 = 0.9f*sc_*a3 + 0.1f*hif(hu.y);
    float r4 = 0.9f*sc_*a4 + 0.1f*lof(hu.z);
    float r5 = 0.9f*sc_*a5 + 0.1f*hif(hu.z);
    float r6 = 0.9f*sc_*a6 + 0.1f*lof(hu.w);
    float r7 = 0.9f*sc_*a7 + 0.1f*hif(hu.w);
    uint4 o;
    o.x = pack2(r0,r1); o.y = pack2(r2,r3); o.z = pack2(r4,r5); o.w = pack2(r6,r7);
    *(uint4*)(featA + (size_t)n*FDIM + cg) = o;
  }
}

// ---------------- hop2 full row + elu + GEMM2 ------------------------------
__global__ __launch_bounds__(256) void k_hop2(const u16* __restrict__ featA, const u16* __restrict__ h0,
                                              const u16* __restrict__ p_all, const __half* __restrict__ scale,
                                              const int* __restrict__ row_start, const int* __restrict__ csr_src,
                                              const float* __restrict__ W_out, float* __restrict__ out0){
  __shared__ float hs[4][FDIM+4];
  int wv = threadIdx.x >> 6, l = threadIdx.x & 63;
  int n = blockIdx.x*4 + wv;
  int half = l >> 5, sl = l & 31;
  int cg = 8*sl;
  int head = sl >> 2;
  float sc_ = __half2float(scale[n*NHEADSC + head]);
  int beg = row_start[n], end = row_start[n+1];
  float a0=0.f,a1=0.f,a2=0.f,a3=0.f,a4=0.f,a5=0.f,a6=0.f,a7=0.f;
  int pos = beg;
  for (; pos+8<=end; pos+=8){
    int e0=csr_src[pos+0+half], e1=csr_src[pos+2+half], e2=csr_src[pos+4+half], e3=csr_src[pos+6+half];
    float p0=b2f(p_all[(size_t)(pos+0+half)*NHEADSC+head]);
    float p1=b2f(p_all[(size_t)(pos+2+half)*NHEADSC+head]);
    float p2=b2f(p_all[(size_t)(pos+4+half)*NHEADSC+head]);
    float p3=b2f(p_all[(size_t)(pos+6+half)*NHEADSC+head]);
    uint4 g0 = *(const uint4*)(featA + (size_t)e0*FDIM + cg);
    uint4 g1 = *(const uint4*)(featA + (size_t)e1*FDIM + cg);
    uint4 g2 = *(const uint4*)(featA + (size_t)e2*FDIM + cg);
    uint4 g3 = *(const uint4*)(featA + (size_t)e3*FDIM + cg);
    ACC8(p0,g0) ACC8(p1,g1) ACC8(p2,g2) ACC8(p3,g3)
  }
  for (; pos+2<=end; pos+=2){
    int e = csr_src[pos+half];
    float p = b2f(p_all[(size_t)(pos+half)*NHEADSC+head]);
    uint4 g = *(const uint4*)(featA + (size_t)e*FDIM + cg);
    ACC8(p, g)
  }
  if (pos < end && half == 0){
    int e = csr_src[pos];
    float p = b2f(p_all[(size_t)pos*NHEADSC+head]);
    uint4 g = *(const uint4*)(featA + (size_t)e*FDIM + cg);
    ACC8(p, g)
  }
  a0 += __shfl_xor(a0, 32); a1 += __shfl_xor(a1, 32);
  a2 += __shfl_xor(a2, 32); a3 += __shfl_xor(a3, 32);
  a4 += __shfl_xor(a4, 32); a5 += __shfl_xor(a5, 32);
  a6 += __shfl_xor(a6, 32); a7 += __shfl_xor(a7, 32);
  if (half == 0){
    uint4 hu = *(const uint4*)(h0 + (size_t)n*FDIM + cg);
    float r0 = 0.9f*sc_*a0 + 0.1f*lof(hu.x);
    float r1 = 0.9f*sc_*a1 + 0.1f*hif(hu.x);
    float r2 = 0.9f*sc_*a2 + 0.1f*lof(hu.y);
    float r3 = 0.9f*sc_*a3 + 0.1f*hif(hu.y);
    float r4 = 0.9f*sc_*a4 + 0.1f*lof(hu.z);
    float r5 = 0.9f*sc_*a5 + 0.1f*hif(hu.z);
    float r6 = 0.9f*sc_*a6 + 0.1f*lof(hu.w);
    float r7 = 0.9f*sc_*a7 + 0.1f*hif(hu.w);
    hs[wv][cg  ] = r0 > 0.f ? r0 : (__expf(r0)-1.0f);
    hs[wv][cg+1] = r1 > 0.f ? r1 : (__expf(r1)-1.0f);
    hs[wv][cg+2] = r2 > 0.f ? r2 : (__expf(r2)-1.0f);
    hs[wv][cg+3] = r3 > 0.f ? r3 : (__expf(r3)-1.0f);
    hs[wv][cg+4] = r4 > 0.f ? r4 : (__expf(r4)-1.0f);
    hs[wv][cg+5] = r5 > 0.f ? r5 : (__expf(r5)-1.0f);
    hs[wv][cg+6] = r6 > 0.f ? r6 : (__expf(r6)-1.0f);
    hs[wv][cg+7] = r7 > 0.f ? r7 : (__expf(r7)-1.0f);
  }
  __syncthreads();
  int t = threadIdx.x;
  if (t < 4*NCLASSC){
    int node = t/NCLASSC, c = t%NCLASSC;
    const float* hv = hs[node];
    const float* wp = W_out + c;
    float o = 0.f;
    #pragma unroll 8
    for (int k=0;k<FDIM;k++) o = fmaf(hv[k], wp[(size_t)k*NCLASSC], o);
    out0[(size_t)(blockIdx.x*4+node)*NCLASSC + c] = o;
  }
}

// ---------------- output-layer s,t + bf16 line-padded copy -----------------
// out0b[n][64]: bf16 copy of out0 row padded to one 128B cache line, so the
// phase-4 gather fetches exactly 1 line/edge (fp32 160B rows spanned ~2.25).
__global__ __launch_bounds__(256) void k_st_out(const float* __restrict__ out0, const float* __restrict__ a_s,
                                                const float* __restrict__ a_d, float* __restrict__ s,
                                                float* __restrict__ t_, u16* __restrict__ out0b){
  int n = blockIdx.x*256 + threadIdx.x;
  if (n >= NN) return;
  const float4* r = (const float4*)(out0 + (size_t)n*NCLASSC);
  uint2* ob = (uint2*)(out0b + (size_t)n*64);
  float ss=0.f, tt=0.f;
  #pragma unroll
  for (int j=0;j<10;j++){
    float4 v = r[j];
    float4 av = *(const float4*)(a_s + 4*j);
    float4 bv = *(const float4*)(a_d + 4*j);
    ss=fmaf(v.x,av.x,ss); tt=fmaf(v.x,bv.x,tt);
    ss=fmaf(v.y,av.y,ss); tt=fmaf(v.y,bv.y,tt);
    ss=fmaf(v.z,av.z,ss); tt=fmaf(v.z,bv.z,tt);
    ss=fmaf(v.w,av.w,ss); tt=fmaf(v.w,bv.w,tt);
    uint2 o; o.x = pack2(v.x,v.y); o.y = pack2(v.z,v.w);
    ob[j] = o;
  }
  s[n]=ss; t_[n]=tt;
}

// ---------------- output-layer attention: p (fp32), unroll x4 --------------
__global__ __launch_bounds__(256) void k_att_out(const float* __restrict__ s, const float* __restrict__ t_,
                                                 const int* __restrict__ row_start, const int* __restrict__ csr_src,
                                                 float* __restrict__ p_out, float* __restrict__ scale_out){
  int n = blockIdx.x*256 + threadIdx.x;
  if (n >= NN) return;
  int beg = row_start[n], end = row_start[n+1];
  float tn = t_[n];
  float d0=0.f,d1=0.f,d2=0.f,d3=0.f;
  int pos = beg;
  for (; pos+4<=end; pos+=4){
    int u0=csr_src[pos], u1=csr_src[pos+1], u2=csr_src[pos+2], u3=csr_src[pos+3];
    float p0=__expf(lrelu(s[u0]+tn));
    float p1=__expf(lrelu(s[u1]+tn));
    float p2=__expf(lrelu(s[u2]+tn));
    float p3=__expf(lrelu(s[u3]+tn));
    p_out[pos]=p0; p_out[pos+1]=p1; p_out[pos+2]=p2; p_out[pos+3]=p3;
    d0+=p0; d1+=p1; d2+=p2; d3+=p3;
  }
  for (; pos<end; pos++){
    float p = __expf(lrelu(s[csr_src[pos]]+tn));
    p_out[pos] = p;
    d0 += p;
  }
  scale_out[n] = 1.0f/(((d0+d1)+(d2+d3)) + 1e-16f);
}

// ---------------- output-layer hop 1 (gathers 1-line bf16 rows) ------------
__global__ __launch_bounds__(64) void k_hop1_out(const float* __restrict__ out0, const u16* __restrict__ out0b,
                                                 const float* __restrict__ p_out, const float* __restrict__ scale_out,
                                                 const int* __restrict__ row_start, const int* __restrict__ csr_src,
                                                 u16* __restrict__ outA){
  int n = blockIdx.x, t = threadIdx.x;
  float sc_ = scale_out[n];
  int beg = row_start[n], end = row_start[n+1];
  int tc = (t < NCLASSC) ? t : 0;
  float a0=0.f,a1=0.f,a2=0.f,a3=0.f;
  int pos = beg;
  for (; pos+4<=end; pos+=4){
    int u0=csr_src[pos], u1=csr_src[pos+1], u2=csr_src[pos+2], u3=csr_src[pos+3];
    float p0=p_out[pos], p1=p_out[pos+1], p2=p_out[pos+2], p3=p_out[pos+3];
    float f0=b2f(out0b[(size_t)u0*64+tc]);
    float f1=b2f(out0b[(size_t)u1*64+tc]);
    float f2=b2f(out0b[(size_t)u2*64+tc]);
    float f3=b2f(out0b[(size_t)u3*64+tc]);
    a0=fmaf(p0,f0,a0); a1=fmaf(p1,f1,a1); a2=fmaf(p2,f2,a2); a3=fmaf(p3,f3,a3);
  }
  for (; pos<end; pos++){
    a0=fmaf(p_out[pos], b2f(out0b[(size_t)csr_src[pos]*64+tc]), a0);
  }
  if (t < NCLASSC){
    float res = 0.9f*sc_*((a0+a1)+(a2+a3)) + 0.1f*out0[(size_t)n*NCLASSC + t];
    outA[(size_t)n*64 + t] = f2b(res);
  }
}

// ---------------- output-layer hop 2 + elu + log_softmax -------------------
__global__ __launch_bounds__(64) void k_hop2_out_final(const u16* __restrict__ outA, const float* __restrict__ out0,
                                                       const float* __restrict__ p_out, const float* __restrict__ scale_out,
                                                       const int* __restrict__ row_start, const int* __restrict__ csr_src,
                                                       float* __restrict__ out){
  int n = blockIdx.x, t = threadIdx.x;
  float sc_ = scale_out[n];
  int beg = row_start[n], end = row_start[n+1];
  int tc = (t < NCLASSC) ? t : 0;
  float a0=0.f,a1=0.f,a2=0.f,a3=0.f;
  int pos = beg;
  for (; pos+4<=end; pos+=4){
    int u0=csr_src[pos], u1=csr_src[pos+1], u2=csr_src[pos+2], u3=csr_src[pos+3];
    float p0=p_out[pos], p1=p_out[pos+1], p2=p_out[pos+2], p3=p_out[pos+3];
    float f0=b2f(outA[(size_t)u0*64+tc]);
    float f1=b2f(outA[(size_t)u1*64+tc]);
    float f2=b2f(outA[(size_t)u2*64+tc]);
    float f3=b2f(outA[(size_t)u3*64+tc]);
    a0=fmaf(p0,f0,a0); a1=fmaf(p1,f1,a1); a2=fmaf(p2,f2,a2); a3=fmaf(p3,f3,a3);
  }
  for (; pos<end; pos++){
    a0=fmaf(p_out[pos], b2f(outA[(size_t)csr_src[pos]*64+tc]), a0);
  }
  float v = -1e30f;
  if (t < NCLASSC){
    float res = 0.9f*sc_*((a0+a1)+(a2+a3)) + 0.1f*out0[(size_t)n*NCLASSC + t];
    v = res > 0.f ? res : (__expf(res)-1.0f);
  }
  float m = v;
  #pragma unroll
  for (int off=32; off; off>>=1) m = fmaxf(m, __shfl_xor(m, off));
  float ex = (t < NCLASSC) ? __expf(v - m) : 0.f;
  float ssum = ex;
  #pragma unroll
  for (int off=32; off; off>>=1) ssum += __shfl_xor(ssum, off);
  if (t < NCLASSC) out[(size_t)n*NCLASSC + t] = v - m - __logf(ssum);
}

extern "C" void kernel_launch(void* const* d_in, const int* in_sizes, int n_in,
                              void* d_out, int out_size, void* d_ws, size_t ws_size,
                              hipStream_t stream){
  const float* x        = (const float*)d_in[0];
  const int*   ei       = (const int*)d_in[1];
  const float* W        = (const float*)d_in[2];
  const float* a_src    = (const float*)d_in[3];
  const float* a_dst    = (const float*)d_in[4];
  const float* W_out    = (const float*)d_in[5];
  const float* a_src_o  = (const float*)d_in[6];
  const float* a_dst_o  = (const float*)d_in[7];
  float* out            = (float*)d_out;
  const int* e_src = ei;
  const int* e_dst = ei + EE;

  // ---- workspace: ~156.1 MB (< 156.87 MB proven safe) ----
  char* ws = (char*)d_ws;
  size_t off = 0;
  auto alloc = [&](size_t bytes)->char*{ char* p = ws + off; off += (bytes + 255) & ~(size_t)255; return p; };

  u16*    h0        = (u16*)   alloc((size_t)NN*FDIM*2);      // 51.2 MB
  u16*    featA     = (u16*)   alloc((size_t)NN*FDIM*2);      // 51.2 MB (out0b+outA alias after phase 3)
  float*  out0      = (float*) alloc((size_t)NN*NCLASSC*4);   // 16 MB
  int*    csr_src   = (int*)   alloc((size_t)EE*4);           // 6.4 MB
  int*    row_start = (int*)   alloc((size_t)(NN+1)*4);       // 0.4 MB
  char*   regS      =          alloc((size_t)NN*NHEADSC*2*2); // 3.2 MB: s,t then phase-4 smalls
  u16*    p_all     = (u16*)   alloc((size_t)EE*NHEADSC*2);   // 25.6 MB (fp32 p_out aliased later)
  __half* scale     = (__half*)alloc((size_t)NN*NHEADSC*2);   // 1.6 MB
  int*    counts    = (int*)   alloc((size_t)NN*4);           // 0.4 MB
  int*    bsum      = (int*)   alloc((size_t)NBLK*4);
  int*    boff      = (int*)   alloc((size_t)NBLK*4);
  u16*    Wt        = (u16*)   alloc((size_t)FDIM*NFEATC*2);  // 64 KB

  u16*   s         = (u16*)regS;                       // phase 1-3
  u16*   t_        = (u16*)(regS + (size_t)NN*NHEADSC*2);
  float* s_out     = (float*)regS;                     // phase 4 (s,t dead)
  float* t_out     = s_out + NN;
  float* scale_out = t_out + NN;
  u16*   out0b     = (u16*)featA;                      // phase 4 (featA dead): [NN][64] bf16, 12.8 MB
  u16*   outA      = (u16*)featA + (size_t)NN*64;      // phase 4: [NN][64] bf16, 12.8 MB
  float* p_out     = (float*)p_all;                    // phase 4 (p_all dead)

  // phase 1: feature transform (MFMA) + per-head s,t
  k_transposeW<<<(FDIM*NFEATC+255)/256, 256, 0, stream>>>(W, Wt);
  k_gemm1_mfma<<<NN/16, 256, 0, stream>>>(x, Wt, h0);
  k_st<<<(NN*NHEADSC+255)/256, 256, 0, stream>>>(h0, a_src, a_dst, s, t_);

  // phase 2: CSR build (hierarchical scan)
  k_zero<<<(NN+255)/256, 256, 0, stream>>>(counts, NN);
  k_count<<<(EE+255)/256, 256, 0, stream>>>(e_dst, counts);
  k_blocksum<<<NBLK, 256, 0, stream>>>(counts, bsum);
  k_scan_bsum<<<1, 512, 0, stream>>>(bsum, boff);
  k_scan_final<<<NBLK, 256, 0, stream>>>(counts, boff, row_start);
  k_zero<<<(NN+255)/256, 256, 0, stream>>>(counts, NN);
  k_scatter<<<(EE+255)/256, 256, 0, stream>>>(e_src, e_dst, row_start, counts, csr_src);

  // phase 3: attention pass, then full-row hop1 + hop2(+GEMM2)
  k_att<<<(NN*NHEADSC+255)/256, 256, 0, stream>>>(s, t_, row_start, csr_src, p_all, scale);
  k_hop1<<<NN/4, 256, 0, stream>>>(h0, p_all, scale, row_start, csr_src, featA);
  k_hop2<<<NN/4, 256, 0, stream>>>(featA, h0, p_all, scale, row_start, csr_src, W_out, out0);

  // phase 4: output layer (p precomputed fp32; gathers use 1-line bf16 rows)
  k_st_out<<<(NN+255)/256, 256, 0, stream>>>(out0, a_src_o, a_dst_o, s_out, t_out, out0b);
  k_att_out<<<(NN+255)/256, 256, 0, stream>>>(s_out, t_out, row_start, csr_src, p_out, scale_out);
  k_hop1_out<<<NN, 64, 0, stream>>>(out0, out0b, p_out, scale_out, row_start, csr_src, outA);
  k_hop2_out_final<<<NN, 64, 0, stream>>>(outA, out0, p_out, scale_out, row_start, csr_src, out);
}

// Round 8
// 844.425 us; speedup vs baseline: 1.4027x; 1.0043x over previous
//
#include <hip/hip_runtime.h>
#include <hip/hip_fp16.h>
#include <stdint.h>

#define NN      100000
#define EE      1600000
#define NFEATC  128
#define NHIDC   32
#define NHEADSC 8
#define NCLASSC 40
#define FDIM    256     // NHEADS*NHID
#define NBLK    ((NN+255)/256)   // 391

typedef unsigned short u16;
typedef __attribute__((ext_vector_type(8))) short bf16x8;
typedef __attribute__((ext_vector_type(4))) float f32x4;

__device__ __forceinline__ float b2f(u16 u){ union{uint32_t i; float f;} v; v.i=((uint32_t)u)<<16; return v.f; }
__device__ __forceinline__ float lof(uint32_t u){ union{uint32_t i; float f;} v; v.i=u<<16; return v.f; }
__device__ __forceinline__ float hif(uint32_t u){ union{uint32_t i; float f;} v; v.i=u&0xFFFF0000u; return v.f; }
__device__ __forceinline__ u16 f2b(float f){ union{float f; uint32_t i;} v; v.f=f; uint32_t x=v.i; return (u16)((x + 0x7FFFu + ((x>>16)&1u))>>16); }
__device__ __forceinline__ uint32_t pack2(float a, float b){ return (uint32_t)f2b(a) | ((uint32_t)f2b(b)<<16); }
__device__ __forceinline__ float lrelu(float e){ return e > 0.f ? e : 0.2f*e; }

// ---------------- W transpose+cast: Wt[c][k] = bf16(W[head][k][hid]) -------
__global__ __launch_bounds__(256) void k_transposeW(const float* __restrict__ W, u16* __restrict__ Wt){
  int i = blockIdx.x*256 + threadIdx.x;
  if (i >= FDIM*NFEATC) return;
  int c = i >> 7, k = i & 127;
  int head = c >> 5, hid = c & 31;
  Wt[c*NFEATC + k] = f2b(W[head*(NFEATC*NHIDC) + k*NHIDC + hid]);
}

// ---------------- GEMM1 via MFMA: h0 = x @ W  (bf16 out) -------------------
__global__ __launch_bounds__(256) void k_gemm1_mfma(const float* __restrict__ x, const u16* __restrict__ Wt,
                                                    u16* __restrict__ h0){
  int w = threadIdx.x >> 6, lane = threadIdx.x & 63;
  int nt = blockIdx.x;
  int m = lane & 15, q = lane >> 4;
  int row = nt*16 + m;
  int c0 = w*64;
  const float* xrow = x + (size_t)row*NFEATC;
  f32x4 acc0 = {0.f,0.f,0.f,0.f}, acc1 = {0.f,0.f,0.f,0.f};
  f32x4 acc2 = {0.f,0.f,0.f,0.f}, acc3 = {0.f,0.f,0.f,0.f};
  #pragma unroll
  for (int kk=0; kk<NFEATC; kk+=32){
    int ko = kk + q*8;
    float4 xa = *(const float4*)(xrow + ko);
    float4 xb = *(const float4*)(xrow + ko + 4);
    bf16x8 a;
    a[0]=(short)f2b(xa.x); a[1]=(short)f2b(xa.y); a[2]=(short)f2b(xa.z); a[3]=(short)f2b(xa.w);
    a[4]=(short)f2b(xb.x); a[5]=(short)f2b(xb.y); a[6]=(short)f2b(xb.z); a[7]=(short)f2b(xb.w);
    bf16x8 b0 = *(const bf16x8*)(Wt + (size_t)(c0 +  0 + m)*NFEATC + ko);
    bf16x8 b1 = *(const bf16x8*)(Wt + (size_t)(c0 + 16 + m)*NFEATC + ko);
    bf16x8 b2 = *(const bf16x8*)(Wt + (size_t)(c0 + 32 + m)*NFEATC + ko);
    bf16x8 b3 = *(const bf16x8*)(Wt + (size_t)(c0 + 48 + m)*NFEATC + ko);
    acc0 = __builtin_amdgcn_mfma_f32_16x16x32_bf16(a, b0, acc0, 0,0,0);
    acc1 = __builtin_amdgcn_mfma_f32_16x16x32_bf16(a, b1, acc1, 0,0,0);
    acc2 = __builtin_amdgcn_mfma_f32_16x16x32_bf16(a, b2, acc2, 0,0,0);
    acc3 = __builtin_amdgcn_mfma_f32_16x16x32_bf16(a, b3, acc3, 0,0,0);
  }
  #pragma unroll
  for (int r=0; r<4; r++){
    size_t base = (size_t)(nt*16 + q*4 + r)*FDIM + c0 + m;
    h0[base +  0] = f2b(acc0[r]);
    h0[base + 16] = f2b(acc1[r]);
    h0[base + 32] = f2b(acc2[r]);
    h0[base + 48] = f2b(acc3[r]);
  }
}

// ---------------- s,t per (node,head), bf16, vectorized loads --------------
__global__ __launch_bounds__(256) void k_st(const u16* __restrict__ h0, const float* __restrict__ a_src,
                                            const float* __restrict__ a_dst, u16* __restrict__ s,
                                            u16* __restrict__ t_){
  int i = blockIdx.x*256 + threadIdx.x;
  if (i >= NN*NHEADSC) return;
  int n = i>>3, head = i&7;
  const uint4*  hp = (const uint4*)(h0 + (size_t)n*FDIM + head*NHIDC);
  const float4* ap = (const float4*)(a_src + head*NHIDC);
  const float4* bp = (const float4*)(a_dst + head*NHIDC);
  float ss=0.f, tt=0.f;
  #pragma unroll
  for (int j=0;j<4;j++){
    uint4 hv = hp[j];
    float4 a0v=ap[2*j], a1v=ap[2*j+1], b0v=bp[2*j], b1v=bp[2*j+1];
    float h0f=lof(hv.x), h1f=hif(hv.x), h2f=lof(hv.y), h3f=hif(hv.y);
    float h4f=lof(hv.z), h5f=hif(hv.z), h6f=lof(hv.w), h7f=hif(hv.w);
    ss=fmaf(h0f,a0v.x,ss); tt=fmaf(h0f,b0v.x,tt);
    ss=fmaf(h1f,a0v.y,ss); tt=fmaf(h1f,b0v.y,tt);
    ss=fmaf(h2f,a0v.z,ss); tt=fmaf(h2f,b0v.z,tt);
    ss=fmaf(h3f,a0v.w,ss); tt=fmaf(h3f,b0v.w,tt);
    ss=fmaf(h4f,a1v.x,ss); tt=fmaf(h4f,b1v.x,tt);
    ss=fmaf(h5f,a1v.y,ss); tt=fmaf(h5f,b1v.y,tt);
    ss=fmaf(h6f,a1v.z,ss); tt=fmaf(h6f,b1v.z,tt);
    ss=fmaf(h7f,a1v.w,ss); tt=fmaf(h7f,b1v.w,tt);
  }
  s[i]=f2b(ss); t_[i]=f2b(tt);
}

// ---------------- CSR build ------------------------------------------------
__global__ __launch_bounds__(256) void k_zero(int* __restrict__ p, int n){
  int i = blockIdx.x*256 + threadIdx.x;
  if (i < n) p[i] = 0;
}
__global__ __launch_bounds__(256) void k_count(const int* __restrict__ dst, int* __restrict__ counts){
  int e = blockIdx.x*256 + threadIdx.x;
  if (e < EE) atomicAdd(&counts[dst[e]], 1);
}
__global__ __launch_bounds__(256) void k_blocksum(const int* __restrict__ counts, int* __restrict__ bsum){
  __shared__ int wsum[4];
  int b = blockIdx.x, t = threadIdx.x;
  int i = b*256 + t;
  int v = (i < NN) ? counts[i] : 0;
  #pragma unroll
  for (int off=32; off; off>>=1) v += __shfl_xor(v, off);
  if ((t & 63) == 0) wsum[t>>6] = v;
  __syncthreads();
  if (t == 0) bsum[b] = wsum[0]+wsum[1]+wsum[2]+wsum[3];
}
__global__ __launch_bounds__(512) void k_scan_bsum(const int* __restrict__ bsum, int* __restrict__ boff){
  __shared__ int lds[512];
  int t = threadIdx.x;
  int v = (t < NBLK) ? bsum[t] : 0;
  lds[t] = v; __syncthreads();
  for (int off=1; off<512; off<<=1){
    int u = (t>=off) ? lds[t-off] : 0;
    __syncthreads();
    lds[t] += u;
    __syncthreads();
  }
  if (t < NBLK) boff[t] = lds[t] - v;
}
__global__ __launch_bounds__(256) void k_scan_final(const int* __restrict__ counts, const int* __restrict__ boff,
                                                    int* __restrict__ row_start){
  __shared__ int lds[256];
  int b = blockIdx.x, t = threadIdx.x;
  int i = b*256 + t;
  int v = (i < NN) ? counts[i] : 0;
  lds[t] = v; __syncthreads();
  for (int off=1; off<256; off<<=1){
    int u = (t>=off) ? lds[t-off] : 0;
    __syncthreads();
    lds[t] += u;
    __syncthreads();
  }
  if (i < NN) row_start[i] = boff[b] + lds[t] - v;
  if (b == 0 && t == 0) row_start[NN] = EE;
}
__global__ __launch_bounds__(256) void k_scatter(const int* __restrict__ src, const int* __restrict__ dst,
                                                 const int* __restrict__ row_start, int* __restrict__ fill,
                                                 int* __restrict__ csr_src){
  int e = blockIdx.x*256 + threadIdx.x;
  if (e >= EE) return;
  int d = dst[e];
  int pos = row_start[d] + atomicAdd(&fill[d], 1);
  csr_src[pos] = src[e];
}

// ---------------- fused att+hop1: half-wave edge pairs, 8 ch/lane ----------
// p computed inline from s (1.6MB, L2-hot) replacing the p_all read; den
// accumulated from the bf16-ROUNDED p (numerics-identical to old k_att);
// p_all + scale still WRITTEN for hop2's linear coefficient loads (r3 lesson:
// hop2 must not gain a second gather).
#define ACC8(p, g) \
  a0=fmaf(p,lof(g.x),a0); a1=fmaf(p,hif(g.x),a1); \
  a2=fmaf(p,lof(g.y),a2); a3=fmaf(p,hif(g.y),a3); \
  a4=fmaf(p,lof(g.z),a4); a5=fmaf(p,hif(g.z),a5); \
  a6=fmaf(p,lof(g.w),a6); a7=fmaf(p,hif(g.w),a7);

__global__ __launch_bounds__(256) void k_hop1(const u16* __restrict__ h0, const u16* __restrict__ s,
                                              const u16* __restrict__ t_, const int* __restrict__ row_start,
                                              const int* __restrict__ csr_src, u16* __restrict__ featA,
                                              u16* __restrict__ p_all, __half* __restrict__ scale){
  int wv = threadIdx.x >> 6, l = threadIdx.x & 63;
  int n = blockIdx.x*4 + wv;
  int half = l >> 5, sl = l & 31;
  int cg = 8*sl;
  int head = sl >> 2;
  float tn = b2f(t_[n*NHEADSC + head]);
  int beg = row_start[n], end = row_start[n+1];
  float a0=0.f,a1=0.f,a2=0.f,a3=0.f,a4=0.f,a5=0.f,a6=0.f,a7=0.f,den=0.f;
  int pos = beg;
  for (; pos+8<=end; pos+=8){
    int e0=csr_src[pos+0+half], e1=csr_src[pos+2+half], e2=csr_src[pos+4+half], e3=csr_src[pos+6+half];
    float s0=b2f(s[e0*NHEADSC+head]), s1=b2f(s[e1*NHEADSC+head]);
    float s2=b2f(s[e2*NHEADSC+head]), s3=b2f(s[e3*NHEADSC+head]);
    uint4 g0 = *(const uint4*)(h0 + (size_t)e0*FDIM + cg);
    uint4 g1 = *(const uint4*)(h0 + (size_t)e1*FDIM + cg);
    uint4 g2 = *(const uint4*)(h0 + (size_t)e2*FDIM + cg);
    uint4 g3 = *(const uint4*)(h0 + (size_t)e3*FDIM + cg);
    u16 q0=f2b(__expf(lrelu(s0+tn))), q1=f2b(__expf(lrelu(s1+tn)));
    u16 q2=f2b(__expf(lrelu(s2+tn))), q3=f2b(__expf(lrelu(s3+tn)));
    float p0=b2f(q0), p1=b2f(q1), p2=b2f(q2), p3=b2f(q3);
    if ((sl&3)==0){
      p_all[(size_t)(pos+0+half)*NHEADSC+head]=q0;
      p_all[(size_t)(pos+2+half)*NHEADSC+head]=q1;
      p_all[(size_t)(pos+4+half)*NHEADSC+head]=q2;
      p_all[(size_t)(pos+6+half)*NHEADSC+head]=q3;
    }
    den += (p0+p1)+(p2+p3);
    ACC8(p0,g0) ACC8(p1,g1) ACC8(p2,g2) ACC8(p3,g3)
  }
  for (; pos+2<=end; pos+=2){
    int e = csr_src[pos+half];
    float sv = b2f(s[e*NHEADSC+head]);
    uint4 g = *(const uint4*)(h0 + (size_t)e*FDIM + cg);
    u16 q = f2b(__expf(lrelu(sv+tn)));
    float p = b2f(q);
    if ((sl&3)==0) p_all[(size_t)(pos+half)*NHEADSC+head]=q;
    den += p;
    ACC8(p, g)
  }
  if (pos < end && half == 0){
    int e = csr_src[pos];
    float sv = b2f(s[e*NHEADSC+head]);
    uint4 g = *(const uint4*)(h0 + (size_t)e*FDIM + cg);
    u16 q = f2b(__expf(lrelu(sv+tn)));
    float p = b2f(q);
    if ((sl&3)==0) p_all[(size_t)pos*NHEADSC+head]=q;
    den += p;
    ACC8(p, g)
  }
  a0 += __shfl_xor(a0, 32); a1 += __shfl_xor(a1, 32);
  a2 += __shfl_xor(a2, 32); a3 += __shfl_xor(a3, 32);
  a4 += __shfl_xor(a4, 32); a5 += __shfl_xor(a5, 32);
  a6 += __shfl_xor(a6, 32); a7 += __shfl_xor(a7, 32);
  den += __shfl_xor(den, 32);
  float sc_ = 1.0f/(den + 1e-16f);
  if (half == 0 && (sl&3)==0) scale[n*NHEADSC + head] = __float2half(sc_);
  if (half == 0){
    uint4 hu = *(const uint4*)(h0 + (size_t)n*FDIM + cg);
    float r0 = 0.9f*sc_*a0 + 0.1f*lof(hu.x);
    float r1 = 0.9f*sc_*a1 + 0.1f*hif(hu.x);
    float r2 = 0.9f*sc_*a2 + 0.1f*lof(hu.y);
    float r3 = 0.9f*sc_*a3 + 0.1f*hif(hu.y);
    float r4 = 0.9f*sc_*a4 + 0.1f*lof(hu.z);
    float r5 = 0.9f*sc_*a5 + 0.1f*hif(hu.z);
    float r6 = 0.9f*sc_*a6 + 0.1f*lof(hu.w);
    float r7 = 0.9f*sc_*a7 + 0.1f*hif(hu.w);
    uint4 o;
    o.x = pack2(r0,r1); o.y = pack2(r2,r3); o.z = pack2(r4,r5); o.w = pack2(r6,r7);
    *(uint4*)(featA + (size_t)n*FDIM + cg) = o;
  }
}

// ---------------- hop2 full row + elu + GEMM2 (unchanged, r1 best) ---------
__global__ __launch_bounds__(256) void k_hop2(const u16* __restrict__ featA, const u16* __restrict__ h0,
                                              const u16* __restrict__ p_all, const __half* __restrict__ scale,
                                              const int* __restrict__ row_start, const int* __restrict__ csr_src,
                                              const float* __restrict__ W_out, float* __restrict__ out0){
  __shared__ float hs[4][FDIM+4];
  int wv = threadIdx.x >> 6, l = threadIdx.x & 63;
  int n = blockIdx.x*4 + wv;
  int half = l >> 5, sl = l & 31;
  int cg = 8*sl;
  int head = sl >> 2;
  float sc_ = __half2float(scale[n*NHEADSC + head]);
  int beg = row_start[n], end = row_start[n+1];
  float a0=0.f,a1=0.f,a2=0.f,a3=0.f,a4=0.f,a5=0.f,a6=0.f,a7=0.f;
  int pos = beg;
  for (; pos+8<=end; pos+=8){
    int e0=csr_src[pos+0+half], e1=csr_src[pos+2+half], e2=csr_src[pos+4+half], e3=csr_src[pos+6+half];
    float p0=b2f(p_all[(size_t)(pos+0+half)*NHEADSC+head]);
    float p1=b2f(p_all[(size_t)(pos+2+half)*NHEADSC+head]);
    float p2=b2f(p_all[(size_t)(pos+4+half)*NHEADSC+head]);
    float p3=b2f(p_all[(size_t)(pos+6+half)*NHEADSC+head]);
    uint4 g0 = *(const uint4*)(featA + (size_t)e0*FDIM + cg);
    uint4 g1 = *(const uint4*)(featA + (size_t)e1*FDIM + cg);
    uint4 g2 = *(const uint4*)(featA + (size_t)e2*FDIM + cg);
    uint4 g3 = *(const uint4*)(featA + (size_t)e3*FDIM + cg);
    ACC8(p0,g0) ACC8(p1,g1) ACC8(p2,g2) ACC8(p3,g3)
  }
  for (; pos+2<=end; pos+=2){
    int e = csr_src[pos+half];
    float p = b2f(p_all[(size_t)(pos+half)*NHEADSC+head]);
    uint4 g = *(const uint4*)(featA + (size_t)e*FDIM + cg);
    ACC8(p, g)
  }
  if (pos < end && half == 0){
    int e = csr_src[pos];
    float p = b2f(p_all[(size_t)pos*NHEADSC+head]);
    uint4 g = *(const uint4*)(featA + (size_t)e*FDIM + cg);
    ACC8(p, g)
  }
  a0 += __shfl_xor(a0, 32); a1 += __shfl_xor(a1, 32);
  a2 += __shfl_xor(a2, 32); a3 += __shfl_xor(a3, 32);
  a4 += __shfl_xor(a4, 32); a5 += __shfl_xor(a5, 32);
  a6 += __shfl_xor(a6, 32); a7 += __shfl_xor(a7, 32);
  if (half == 0){
    uint4 hu = *(const uint4*)(h0 + (size_t)n*FDIM + cg);
    float r0 = 0.9f*sc_*a0 + 0.1f*lof(hu.x);
    float r1 = 0.9f*sc_*a1 + 0.1f*hif(hu.x);
    float r2 = 0.9f*sc_*a2 + 0.1f*lof(hu.y);
    float r3 = 0.9f*sc_*a3 + 0.1f*hif(hu.y);
    float r4 = 0.9f*sc_*a4 + 0.1f*lof(hu.z);
    float r5 = 0.9f*sc_*a5 + 0.1f*hif(hu.z);
    float r6 = 0.9f*sc_*a6 + 0.1f*lof(hu.w);
    float r7 = 0.9f*sc_*a7 + 0.1f*hif(hu.w);
    hs[wv][cg  ] = r0 > 0.f ? r0 : (__expf(r0)-1.0f);
    hs[wv][cg+1] = r1 > 0.f ? r1 : (__expf(r1)-1.0f);
    hs[wv][cg+2] = r2 > 0.f ? r2 : (__expf(r2)-1.0f);
    hs[wv][cg+3] = r3 > 0.f ? r3 : (__expf(r3)-1.0f);
    hs[wv][cg+4] = r4 > 0.f ? r4 : (__expf(r4)-1.0f);
    hs[wv][cg+5] = r5 > 0.f ? r5 : (__expf(r5)-1.0f);
    hs[wv][cg+6] = r6 > 0.f ? r6 : (__expf(r6)-1.0f);
    hs[wv][cg+7] = r7 > 0.f ? r7 : (__expf(r7)-1.0f);
  }
  __syncthreads();
  int t = threadIdx.x;
  if (t < 4*NCLASSC){
    int node = t/NCLASSC, c = t%NCLASSC;
    const float* hv = hs[node];
    const float* wp = W_out + c;
    float o = 0.f;
    #pragma unroll 8
    for (int k=0;k<FDIM;k++) o = fmaf(hv[k], wp[(size_t)k*NCLASSC], o);
    out0[(size_t)(blockIdx.x*4+node)*NCLASSC + c] = o;
  }
}

// ---------------- output-layer s,t + bf16 line-padded copy -----------------
__global__ __launch_bounds__(256) void k_st_out(const float* __restrict__ out0, const float* __restrict__ a_s,
                                                const float* __restrict__ a_d, float* __restrict__ s,
                                                float* __restrict__ t_, u16* __restrict__ out0b){
  int n = blockIdx.x*256 + threadIdx.x;
  if (n >= NN) return;
  const float4* r = (const float4*)(out0 + (size_t)n*NCLASSC);
  uint2* ob = (uint2*)(out0b + (size_t)n*64);
  float ss=0.f, tt=0.f;
  #pragma unroll
  for (int j=0;j<10;j++){
    float4 v = r[j];
    float4 av = *(const float4*)(a_s + 4*j);
    float4 bv = *(const float4*)(a_d + 4*j);
    ss=fmaf(v.x,av.x,ss); tt=fmaf(v.x,bv.x,tt);
    ss=fmaf(v.y,av.y,ss); tt=fmaf(v.y,bv.y,tt);
    ss=fmaf(v.z,av.z,ss); tt=fmaf(v.z,bv.z,tt);
    ss=fmaf(v.w,av.w,ss); tt=fmaf(v.w,bv.w,tt);
    uint2 o; o.x = pack2(v.x,v.y); o.y = pack2(v.z,v.w);
    ob[j] = o;
  }
  s[n]=ss; t_[n]=tt;
}

// ---------------- output-layer attention: p (fp32), unroll x4 --------------
__global__ __launch_bounds__(256) void k_att_out(const float* __restrict__ s, const float* __restrict__ t_,
                                                 const int* __restrict__ row_start, const int* __restrict__ csr_src,
                                                 float* __restrict__ p_out, float* __restrict__ scale_out){
  int n = blockIdx.x*256 + threadIdx.x;
  if (n >= NN) return;
  int beg = row_start[n], end = row_start[n+1];
  float tn = t_[n];
  float d0=0.f,d1=0.f,d2=0.f,d3=0.f;
  int pos = beg;
  for (; pos+4<=end; pos+=4){
    int u0=csr_src[pos], u1=csr_src[pos+1], u2=csr_src[pos+2], u3=csr_src[pos+3];
    float p0=__expf(lrelu(s[u0]+tn));
    float p1=__expf(lrelu(s[u1]+tn));
    float p2=__expf(lrelu(s[u2]+tn));
    float p3=__expf(lrelu(s[u3]+tn));
    p_out[pos]=p0; p_out[pos+1]=p1; p_out[pos+2]=p2; p_out[pos+3]=p3;
    d0+=p0; d1+=p1; d2+=p2; d3+=p3;
  }
  for (; pos<end; pos++){
    float p = __expf(lrelu(s[csr_src[pos]]+tn));
    p_out[pos] = p;
    d0 += p;
  }
  scale_out[n] = 1.0f/(((d0+d1)+(d2+d3)) + 1e-16f);
}

// ---------------- output-layer hop 1 (gathers 1-line bf16 rows) ------------
__global__ __launch_bounds__(64) void k_hop1_out(const float* __restrict__ out0, const u16* __restrict__ out0b,
                                                 const float* __restrict__ p_out, const float* __restrict__ scale_out,
                                                 const int* __restrict__ row_start, const int* __restrict__ csr_src,
                                                 u16* __restrict__ outA){
  int n = blockIdx.x, t = threadIdx.x;
  float sc_ = scale_out[n];
  int beg = row_start[n], end = row_start[n+1];
  int tc = (t < NCLASSC) ? t : 0;
  float a0=0.f,a1=0.f,a2=0.f,a3=0.f;
  int pos = beg;
  for (; pos+4<=end; pos+=4){
    int u0=csr_src[pos], u1=csr_src[pos+1], u2=csr_src[pos+2], u3=csr_src[pos+3];
    float p0=p_out[pos], p1=p_out[pos+1], p2=p_out[pos+2], p3=p_out[pos+3];
    float f0=b2f(out0b[(size_t)u0*64+tc]);
    float f1=b2f(out0b[(size_t)u1*64+tc]);
    float f2=b2f(out0b[(size_t)u2*64+tc]);
    float f3=b2f(out0b[(size_t)u3*64+tc]);
    a0=fmaf(p0,f0,a0); a1=fmaf(p1,f1,a1); a2=fmaf(p2,f2,a2); a3=fmaf(p3,f3,a3);
  }
  for (; pos<end; pos++){
    a0=fmaf(p_out[pos], b2f(out0b[(size_t)csr_src[pos]*64+tc]), a0);
  }
  if (t < NCLASSC){
    float res = 0.9f*sc_*((a0+a1)+(a2+a3)) + 0.1f*out0[(size_t)n*NCLASSC + t];
    outA[(size_t)n*64 + t] = f2b(res);
  }
}

// ---------------- output-layer hop 2 + elu + log_softmax -------------------
__global__ __launch_bounds__(64) void k_hop2_out_final(const u16* __restrict__ outA, const float* __restrict__ out0,
                                                       const float* __restrict__ p_out, const float* __restrict__ scale_out,
                                                       const int* __restrict__ row_start, const int* __restrict__ csr_src,
                                                       float* __restrict__ out){
  int n = blockIdx.x, t = threadIdx.x;
  float sc_ = scale_out[n];
  int beg = row_start[n], end = row_start[n+1];
  int tc = (t < NCLASSC) ? t : 0;
  float a0=0.f,a1=0.f,a2=0.f,a3=0.f;
  int pos = beg;
  for (; pos+4<=end; pos+=4){
    int u0=csr_src[pos], u1=csr_src[pos+1], u2=csr_src[pos+2], u3=csr_src[pos+3];
    float p0=p_out[pos], p1=p_out[pos+1], p2=p_out[pos+2], p3=p_out[pos+3];
    float f0=b2f(outA[(size_t)u0*64+tc]);
    float f1=b2f(outA[(size_t)u1*64+tc]);
    float f2=b2f(outA[(size_t)u2*64+tc]);
    float f3=b2f(outA[(size_t)u3*64+tc]);
    a0=fmaf(p0,f0,a0); a1=fmaf(p1,f1,a1); a2=fmaf(p2,f2,a2); a3=fmaf(p3,f3,a3);
  }
  for (; pos<end; pos++){
    a0=fmaf(p_out[pos], b2f(outA[(size_t)csr_src[pos]*64+tc]), a0);
  }
  float v = -1e30f;
  if (t < NCLASSC){
    float res = 0.9f*sc_*((a0+a1)+(a2+a3)) + 0.1f*out0[(size_t)n*NCLASSC + t];
    v = res > 0.f ? res : (__expf(res)-1.0f);
  }
  float m = v;
  #pragma unroll
  for (int off=32; off; off>>=1) m = fmaxf(m, __shfl_xor(m, off));
  float ex = (t < NCLASSC) ? __expf(v - m) : 0.f;
  float ssum = ex;
  #pragma unroll
  for (int off=32; off; off>>=1) ssum += __shfl_xor(ssum, off);
  if (t < NCLASSC) out[(size_t)n*NCLASSC + t] = v - m - __logf(ssum);
}

extern "C" void kernel_launch(void* const* d_in, const int* in_sizes, int n_in,
                              void* d_out, int out_size, void* d_ws, size_t ws_size,
                              hipStream_t stream){
  const float* x        = (const float*)d_in[0];
  const int*   ei       = (const int*)d_in[1];
  const float* W        = (const float*)d_in[2];
  const float* a_src    = (const float*)d_in[3];
  const float* a_dst    = (const float*)d_in[4];
  const float* W_out    = (const float*)d_in[5];
  const float* a_src_o  = (const float*)d_in[6];
  const float* a_dst_o  = (const float*)d_in[7];
  float* out            = (float*)d_out;
  const int* e_src = ei;
  const int* e_dst = ei + EE;

  // ---- workspace: ~156.1 MB (< 156.87 MB proven safe) ----
  char* ws = (char*)d_ws;
  size_t off = 0;
  auto alloc = [&](size_t bytes)->char*{ char* p = ws + off; off += (bytes + 255) & ~(size_t)255; return p; };

  u16*    h0        = (u16*)   alloc((size_t)NN*FDIM*2);      // 51.2 MB
  u16*    featA     = (u16*)   alloc((size_t)NN*FDIM*2);      // 51.2 MB (out0b+outA alias after phase 3)
  float*  out0      = (float*) alloc((size_t)NN*NCLASSC*4);   // 16 MB
  int*    csr_src   = (int*)   alloc((size_t)EE*4);           // 6.4 MB
  int*    row_start = (int*)   alloc((size_t)(NN+1)*4);       // 0.4 MB
  char*   regS      =          alloc((size_t)NN*NHEADSC*2*2); // 3.2 MB: s,t then phase-4 smalls
  u16*    p_all     = (u16*)   alloc((size_t)EE*NHEADSC*2);   // 25.6 MB (fp32 p_out aliased later)
  __half* scale     = (__half*)alloc((size_t)NN*NHEADSC*2);   // 1.6 MB
  int*    counts    = (int*)   alloc((size_t)NN*4);           // 0.4 MB
  int*    bsum      = (int*)   alloc((size_t)NBLK*4);
  int*    boff      = (int*)   alloc((size_t)NBLK*4);
  u16*    Wt        = (u16*)   alloc((size_t)FDIM*NFEATC*2);  // 64 KB

  u16*   s         = (u16*)regS;                       // phase 1-3
  u16*   t_        = (u16*)(regS + (size_t)NN*NHEADSC*2);
  float* s_out     = (float*)regS;                     // phase 4 (s,t dead)
  float* t_out     = s_out + NN;
  float* scale_out = t_out + NN;
  u16*   out0b     = (u16*)featA;                      // phase 4 (featA dead): [NN][64] bf16, 12.8 MB
  u16*   outA      = (u16*)featA + (size_t)NN*64;      // phase 4: [NN][64] bf16, 12.8 MB
  float* p_out     = (float*)p_all;                    // phase 4 (p_all dead)

  // phase 1: feature transform (MFMA) + per-head s,t
  k_transposeW<<<(FDIM*NFEATC+255)/256, 256, 0, stream>>>(W, Wt);
  k_gemm1_mfma<<<NN/16, 256, 0, stream>>>(x, Wt, h0);
  k_st<<<(NN*NHEADSC+255)/256, 256, 0, stream>>>(h0, a_src, a_dst, s, t_);

  // phase 2: CSR build (hierarchical scan)
  k_zero<<<(NN+255)/256, 256, 0, stream>>>(counts, NN);
  k_count<<<(EE+255)/256, 256, 0, stream>>>(e_dst, counts);
  k_blocksum<<<NBLK, 256, 0, stream>>>(counts, bsum);
  k_scan_bsum<<<1, 512, 0, stream>>>(bsum, boff);
  k_scan_final<<<NBLK, 256, 0, stream>>>(counts, boff, row_start);
  k_zero<<<(NN+255)/256, 256, 0, stream>>>(counts, NN);
  k_scatter<<<(EE+255)/256, 256, 0, stream>>>(e_src, e_dst, row_start, counts, csr_src);

  // phase 3: fused att+hop1 (writes p_all+scale), then hop2(+GEMM2)
  k_hop1<<<NN/4, 256, 0, stream>>>(h0, s, t_, row_start, csr_src, featA, p_all, scale);
  k_hop2<<<NN/4, 256, 0, stream>>>(featA, h0, p_all, scale, row_start, csr_src, W_out, out0);

  // phase 4: output layer (p precomputed fp32; gathers use 1-line bf16 rows)
  k_st_out<<<(NN+255)/256, 256, 0, stream>>>(out0, a_src_o, a_dst_o, s_out, t_out, out0b);
  k_att_out<<<(NN+255)/256, 256, 0, stream>>>(s_out, t_out, row_start, csr_src, p_out, scale_out);
  k_hop1_out<<<NN, 64, 0, stream>>>(out0, out0b, p_out, scale_out, row_start, csr_src, outA);
  k_hop2_out_final<<<NN, 64, 0, stream>>>(outA, out0, p_out, scale_out, row_start, csr_src, out);
}